// Round 2
// baseline (155.227 us; speedup 1.0000x reference)
//
#include <hip/hip_runtime.h>
#include <stdint.h>

// DecisionTree: out = sum_l p_l * (x @ W_l^T + b_l), p from bottom-layer sigmoids.
// Pair-folded: out = x@Wsum^T + bsum + sum_j p_j*(x@dW_j^T + db_j)  -> 9 GEMMs.
// NEW path: pre-scale A by p per leaf -> ONE plain GEMM [4096x9216]@[9216x1024]^T,
// single accumulator (occupancy fix), bias folded into epilogue.

#define M_TOK 4096
#define DDIM  1024
#define NEFF  9

typedef __bf16 bf16x8 __attribute__((ext_vector_type(8)));
typedef float  f32x4  __attribute__((ext_vector_type(4)));
typedef unsigned short u16x4 __attribute__((ext_vector_type(4)));
typedef unsigned short u16x8 __attribute__((ext_vector_type(8)));

#define GLB(p) ((const __attribute__((address_space(1))) void*)(p))
#define LDS(p) ((__attribute__((address_space(3))) void*)(p))

__device__ __forceinline__ unsigned short f2bf(float f) {
    union { float f; uint32_t u; } v; v.f = f;
    uint32_t u = v.u;
    return (unsigned short)((u + 0x7fffu + ((u >> 16) & 1u)) >> 16);  // RNE
}

// ---------------- prep: W' (8 deltas + sum) fp32->bf16, bias table ----------------
__global__ __launch_bounds__(256) void prep_w_kernel(
    const float* __restrict__ lw, const float* __restrict__ lb,
    unsigned short* __restrict__ wp, float* __restrict__ bw)
{
    int idx = blockIdx.x * 256 + threadIdx.x;     // 262144 threads: (o, k/4)
    int o  = idx >> 8;
    int k4 = (idx & 255) << 2;
    size_t base = (size_t)o * DDIM + k4;
    float4 acc = make_float4(0.f, 0.f, 0.f, 0.f);
#pragma unroll
    for (int j = 0; j < 8; ++j) {
        const float4 a = *(const float4*)(lw + (size_t)(2*j)   * DDIM*DDIM + base);
        const float4 b = *(const float4*)(lw + (size_t)(2*j+1) * DDIM*DDIM + base);
        u16x4 d;
        d[0] = f2bf(a.x - b.x); d[1] = f2bf(a.y - b.y);
        d[2] = f2bf(a.z - b.z); d[3] = f2bf(a.w - b.w);
        *(u16x4*)(wp + (size_t)j * DDIM*DDIM + base) = d;
        acc.x += b.x; acc.y += b.y; acc.z += b.z; acc.w += b.w;
    }
    u16x4 s;
    s[0] = f2bf(acc.x); s[1] = f2bf(acc.y); s[2] = f2bf(acc.z); s[3] = f2bf(acc.w);
    *(u16x4*)(wp + (size_t)8 * DDIM*DDIM + base) = s;
    if ((idx & 255) == 0) {                       // one thread per o does the biases
        float sb = 0.f;
#pragma unroll
        for (int j = 0; j < 8; ++j) {
            float ba = lb[(2*j) * DDIM + o];
            float bb = lb[(2*j+1) * DDIM + o];
            bw[j * DDIM + o] = ba - bb;
            sb += bb;
        }
        bw[8 * DDIM + o] = sb;
    }
}

// ---------------- dec2: per-token wave: 8 sigmoids, write 9 scaled bf16 copies ----
__global__ __launch_bounds__(256) void dec2_kernel(
    const float* __restrict__ x, const float* __restrict__ dw,
    const float* __restrict__ db, unsigned short* __restrict__ xs,
    float* __restrict__ pmat)
{
    int m    = blockIdx.x * 4 + (threadIdx.x >> 6);
    int lane = threadIdx.x & 63;
    const float* xr = x + (size_t)m * DDIM + lane * 16;   // lane owns 16 contiguous k
    float xv[16];
    *(float4*)&xv[0]  = *(const float4*)(xr + 0);
    *(float4*)&xv[4]  = *(const float4*)(xr + 4);
    *(float4*)&xv[8]  = *(const float4*)(xr + 8);
    *(float4*)&xv[12] = *(const float4*)(xr + 12);
    float s[8];
#pragma unroll
    for (int j = 0; j < 8; ++j) {
        const float* wr = dw + (size_t)(7 + j) * DDIM + lane * 16;
        float a = 0.f;
#pragma unroll
        for (int i = 0; i < 16; i += 4) {
            float4 wv = *(const float4*)(wr + i);
            a = fmaf(xv[i], wv.x, fmaf(xv[i+1], wv.y, fmaf(xv[i+2], wv.z, fmaf(xv[i+3], wv.w, a))));
        }
        s[j] = a;
    }
#pragma unroll
    for (int j = 0; j < 8; ++j)
#pragma unroll
        for (int off = 32; off > 0; off >>= 1)
            s[j] += __shfl_xor(s[j], off);
    float p[8];
#pragma unroll
    for (int j = 0; j < 8; ++j)
        p[j] = 1.0f / (1.0f + expf(-(s[j] + db[7 + j])));
    if (lane == 0) {
#pragma unroll
        for (int j = 0; j < 8; ++j)
            pmat[(size_t)m * 8 + j] = p[j];
    }
#pragma unroll
    for (int j = 0; j < 9; ++j) {
        float pj = (j < 8) ? p[j] : 1.0f;
        unsigned short* dst = xs + ((size_t)j * M_TOK + m) * DDIM + lane * 16;
#pragma unroll
        for (int c = 0; c < 2; ++c) {
            u16x8 o;
#pragma unroll
            for (int e = 0; e < 8; ++e) o[e] = f2bf(pj * xv[c * 8 + e]);
            *(u16x8*)(dst + c * 8) = o;
        }
    }
}

// -------- tree_gemm2: plain GEMM K=9216, 128x128 tile, BK=32, single acc --------
__global__ __launch_bounds__(256, 2) void tree_gemm2(
    const unsigned short* __restrict__ xs,   // [9][4096][1024] bf16 (p-scaled)
    const unsigned short* __restrict__ wp,   // [9][1024][1024] bf16
    const float* __restrict__ bw,            // [9][1024]
    const float* __restrict__ pmat,          // [4096][8]
    float* __restrict__ out,                 // [4096][1024]
    float* __restrict__ parts)               // [2][4096][1024]
{
    __shared__ __align__(16) unsigned short Asm[2][128 * 32];
    __shared__ __align__(16) unsigned short Bsm[2][128 * 32];

    const int tid  = threadIdx.x;
    const int lane = tid & 63;
    const int w    = tid >> 6;
    const int wm   = w >> 1, wn = w & 1;
    const int bx   = blockIdx.x;        // 0..255
    const int mt   = bx >> 3, nt = bx & 7;
    const int m0   = mt * 128, n0 = nt * 128;
    const int g    = blockIdx.y;        // 0..2, 3 leaves each
    const int leaf0 = g * 3;
    const int ra   = lane & 15;
    const int kb   = (lane >> 4) * 8;

    f32x4 acc[4][4] = {};

    auto stage = [&](int buf, int leaf, int kk) {
#pragma unroll
        for (int c = 0; c < 2; ++c) {
            int row = w * 32 + c * 16 + (lane >> 2);
            int ke  = kk * 32 + (lane & 3) * 8;
            const unsigned short* ga = xs + ((size_t)(leaf * M_TOK) + m0 + row) * DDIM + ke;
            __builtin_amdgcn_global_load_lds(GLB(ga), LDS(&Asm[buf][w * 1024 + c * 512]), 16, 0, 0);
            const unsigned short* gb = wp + ((size_t)(leaf * DDIM) + n0 + row) * DDIM + ke;
            __builtin_amdgcn_global_load_lds(GLB(gb), LDS(&Bsm[buf][w * 1024 + c * 512]), 16, 0, 0);
        }
    };

    const int TOT = 96;                 // 3 leaves x 32 K-steps
    stage(0, leaf0, 0);
    __syncthreads();
    int cur = 0;
    for (int t = 0; t < TOT; ++t) {
        int nxt = t + 1;
        if (nxt < TOT) stage(cur ^ 1, leaf0 + (nxt >> 5), nxt & 31);

        bf16x8 av[4], bv[4];
#pragma unroll
        for (int i = 0; i < 4; ++i)
            av[i] = *(const bf16x8*)&Asm[cur][(wm * 64 + i * 16 + ra) * 32 + kb];
#pragma unroll
        for (int j = 0; j < 4; ++j)
            bv[j] = *(const bf16x8*)&Bsm[cur][(wn * 64 + j * 16 + ra) * 32 + kb];
#pragma unroll
        for (int i = 0; i < 4; ++i)
#pragma unroll
            for (int j = 0; j < 4; ++j)
                acc[i][j] = __builtin_amdgcn_mfma_f32_16x16x32_bf16(av[i], bv[j], acc[i][j], 0, 0, 0);

        __syncthreads();
        cur ^= 1;
    }

    // epilogue: add bias term sum_{l in group} p_l * bw[l][col] (p=1 for leaf 8)
    float* dst = (g == 0) ? out : parts + (size_t)(g - 1) * M_TOK * DDIM;
    float bb[3][4];
#pragma unroll
    for (int c = 0; c < 3; ++c)
#pragma unroll
        for (int j = 0; j < 4; ++j)
            bb[c][j] = bw[(leaf0 + c) * DDIM + n0 + wn * 64 + j * 16 + ra];
#pragma unroll
    for (int i = 0; i < 4; ++i)
#pragma unroll
        for (int r = 0; r < 4; ++r) {
            int row = m0 + wm * 64 + i * 16 + (lane >> 4) * 4 + r;
            float pv[3];
#pragma unroll
            for (int c = 0; c < 3; ++c) {
                int l = leaf0 + c;
                pv[c] = (l < 8) ? pmat[(size_t)row * 8 + l] : 1.0f;
            }
#pragma unroll
            for (int j = 0; j < 4; ++j) {
                float v = acc[i][j][r] + pv[0] * bb[0][j] + pv[1] * bb[1][j] + pv[2] * bb[2][j];
                dst[(size_t)row * DDIM + n0 + wn * 64 + j * 16 + ra] = v;
            }
        }
}

// ================= OLD (fallback) path: dual-acc fused gemm =================
__global__ __launch_bounds__(256) void dec_kernel(
    const float* __restrict__ x, const float* __restrict__ dw,
    const float* __restrict__ db, unsigned short* __restrict__ xb,
    float* __restrict__ pmat)
{
    int m    = blockIdx.x * 4 + (threadIdx.x >> 6);
    int lane = threadIdx.x & 63;
    const float* xr = x + (size_t)m * DDIM;
    unsigned short* xo = xb + (size_t)m * DDIM;
    float s[8] = {0.f,0.f,0.f,0.f,0.f,0.f,0.f,0.f};
#pragma unroll
    for (int i = 0; i < 16; ++i) {
        int k = lane + i * 64;
        float v = xr[k];
        xo[k] = f2bf(v);
#pragma unroll
        for (int j = 0; j < 8; ++j)
            s[j] = fmaf(v, dw[(7 + j) * DDIM + k], s[j]);
    }
#pragma unroll
    for (int j = 0; j < 8; ++j)
#pragma unroll
        for (int off = 32; off > 0; off >>= 1)
            s[j] += __shfl_xor(s[j], off);
    if (lane < 8) {
        float t = s[lane] + db[7 + lane];
        pmat[(size_t)m * 8 + lane] = 1.0f / (1.0f + expf(-t));
    }
}

__global__ __launch_bounds__(256, 2) void tree_gemm(
    const unsigned short* __restrict__ xb, const unsigned short* __restrict__ wp,
    const float* __restrict__ bw, const float* __restrict__ pmat,
    float* __restrict__ out, float* __restrict__ parts)
{
    __shared__ __align__(16) unsigned short Asm[2][128 * 32];
    __shared__ __align__(16) unsigned short Bsm[2][128 * 32];
    __shared__ float Psm[128][8];

    const int tid  = threadIdx.x;
    const int lane = tid & 63;
    const int w    = tid >> 6;
    const int wm   = w >> 1, wn = w & 1;
    const int bx   = blockIdx.x;
    const int mt   = bx >> 3, nt = bx & 7;
    const int m0   = mt * 128, n0 = nt * 128;
    const int g    = blockIdx.y;
    const int lpg  = NEFF / gridDim.y;
    const int leaf0 = g * lpg;
    const int ra   = lane & 15;
    const int kb   = (lane >> 4) * 8;

    ((float4*)&Psm[0][0])[tid] = ((const float4*)(pmat + (size_t)m0 * 8))[tid];

    f32x4 acc[4][4]  = {};
    f32x4 oacc[4][4] = {};

    auto stage = [&](int buf, int leaf, int kk) {
#pragma unroll
        for (int c = 0; c < 2; ++c) {
            int row = w * 32 + c * 16 + (lane >> 2);
            int ke  = kk * 32 + (lane & 3) * 8;
            const unsigned short* ga = xb + (size_t)(m0 + row) * DDIM + ke;
            __builtin_amdgcn_global_load_lds(GLB(ga), LDS(&Asm[buf][w * 1024 + c * 512]), 16, 0, 0);
            const unsigned short* gb = wp + (size_t)(leaf * DDIM + n0 + row) * DDIM + ke;
            __builtin_amdgcn_global_load_lds(GLB(gb), LDS(&Bsm[buf][w * 1024 + c * 512]), 16, 0, 0);
        }
    };

    const int TOT = lpg * 32;
    stage(0, leaf0, 0);
    __syncthreads();
    int cur = 0;
    for (int t = 0; t < TOT; ++t) {
        int nxt = t + 1;
        if (nxt < TOT) stage(cur ^ 1, leaf0 + (nxt >> 5), nxt & 31);

        bf16x8 av[4], bv[4];
#pragma unroll
        for (int i = 0; i < 4; ++i)
            av[i] = *(const bf16x8*)&Asm[cur][(wm * 64 + i * 16 + ra) * 32 + kb];
#pragma unroll
        for (int j = 0; j < 4; ++j)
            bv[j] = *(const bf16x8*)&Bsm[cur][(wn * 64 + j * 16 + ra) * 32 + kb];
#pragma unroll
        for (int i = 0; i < 4; ++i)
#pragma unroll
            for (int j = 0; j < 4; ++j)
                acc[i][j] = __builtin_amdgcn_mfma_f32_16x16x32_bf16(av[i], bv[j], acc[i][j], 0, 0, 0);

        if ((t & 31) == 31) {
            int leaf = leaf0 + (t >> 5);
            float bb[4];
#pragma unroll
            for (int j = 0; j < 4; ++j)
                bb[j] = bw[leaf * DDIM + n0 + wn * 64 + j * 16 + ra];
#pragma unroll
            for (int i = 0; i < 4; ++i) {
                int rbase = wm * 64 + i * 16 + (lane >> 4) * 4;
#pragma unroll
                for (int r = 0; r < 4; ++r) {
                    float pv = (leaf < 8) ? Psm[rbase + r][leaf] : 1.0f;
#pragma unroll
                    for (int j = 0; j < 4; ++j) {
                        oacc[i][j][r] += pv * (acc[i][j][r] + bb[j]);
                        acc[i][j][r] = 0.f;
                    }
                }
            }
        }
        __syncthreads();
        cur ^= 1;
    }

    float* dst = (g == 0) ? out : parts + (size_t)(g - 1) * M_TOK * DDIM;
#pragma unroll
    for (int i = 0; i < 4; ++i)
#pragma unroll
        for (int r = 0; r < 4; ++r) {
            int row = m0 + wm * 64 + i * 16 + (lane >> 4) * 4 + r;
#pragma unroll
            for (int j = 0; j < 4; ++j) {
                int col = n0 + wn * 64 + j * 16 + ra;
                dst[(size_t)row * DDIM + col] = oacc[i][j][r];
            }
        }
}

// ---------------- reduce: out += parts[0] + parts[1] ----------------
__global__ __launch_bounds__(256) void reduce_kernel(
    float* __restrict__ out, const float* __restrict__ parts)
{
    size_t i = (size_t)blockIdx.x * 256 + threadIdx.x;
    float4 a = ((const float4*)out)[i];
    float4 b = ((const float4*)parts)[i];
    float4 c = ((const float4*)(parts + (size_t)M_TOK * DDIM))[i];
    float4 r;
    r.x = a.x + b.x + c.x; r.y = a.y + b.y + c.y;
    r.z = a.z + b.z + c.z; r.w = a.w + b.w + c.w;
    ((float4*)out)[i] = r;
}

extern "C" void kernel_launch(void* const* d_in, const int* in_sizes, int n_in,
                              void* d_out, int out_size, void* d_ws, size_t ws_size,
                              hipStream_t stream) {
    (void)in_sizes; (void)n_in; (void)out_size;
    const float* x     = (const float*)d_in[0];
    const float* dec_w = (const float*)d_in[1];
    const float* dec_b = (const float*)d_in[2];
    const float* lw    = (const float*)d_in[3];
    const float* lb    = (const float*)d_in[4];
    float* out = (float*)d_out;
    uint8_t* w8 = (uint8_t*)d_ws;

    // ---- new path: xs 72MB | wp 18MB | bw | pmat | parts 32MB = 122.2 MiB ----
    const size_t NEED_NEW = 128094208;
    // ---- old path sizes ----
    const size_t NEED_OLD3 = 60985344;
    const size_t NEED_OLD1 = 27430912;

    if (ws_size >= NEED_NEW) {
        unsigned short* xsc  = (unsigned short*)(w8);
        unsigned short* wp   = (unsigned short*)(w8 + 75497472);
        float*          bw   = (float*)(w8 + 94371840);
        float*          pmat = (float*)(w8 + 94408704);
        float*          parts= (float*)(w8 + 94539776);
        prep_w_kernel<<<1024, 256, 0, stream>>>(lw, lb, wp, bw);
        dec2_kernel<<<1024, 256, 0, stream>>>(x, dec_w, dec_b, xsc, pmat);
        tree_gemm2<<<dim3(256, 3), 256, 0, stream>>>(xsc, wp, bw, pmat, out, parts);
        reduce_kernel<<<4096, 256, 0, stream>>>(out, parts);
        return;
    }

    // fallback: round-1 proven path
    unsigned short* xb   = (unsigned short*)(w8);
    unsigned short* wp   = (unsigned short*)(w8 + 8388608);
    float*          bw   = (float*)(w8 + 27262976);
    float*          pmat = (float*)(w8 + 27299840);
    float*          parts= (float*)(w8 + 27430912);
    if (ws_size < NEED_OLD1) return;

    prep_w_kernel<<<1024, 256, 0, stream>>>(lw, lb, wp, bw);
    dec_kernel<<<1024, 256, 0, stream>>>(x, dec_w, dec_b, xb, pmat);
    int ngroups = (ws_size >= NEED_OLD3) ? 3 : 1;
    tree_gemm<<<dim3(256, ngroups), 256, 0, stream>>>(xb, wp, bw, pmat, out, parts);
    if (ngroups == 3)
        reduce_kernel<<<4096, 256, 0, stream>>>(out, parts);
}

// Round 3
// 149.854 us; speedup vs baseline: 1.0359x; 1.0359x over previous
//
#include <hip/hip_runtime.h>
#include <stdint.h>

// DecisionTree: out = sum_l p_l * (x @ W_l^T + b_l), p from bottom-layer sigmoids.
// Pair-folded + A-prescaled: ONE flat GEMM A[4096x9216] @ B[1024x9216]^T,
// A = [p_0*x | p_1*x | ... | p_7*x | x], B = [dW_0 | ... | dW_7 | Wsum] (flat K).
// Bias sum_l p_l*b'_l added in group-0 epilogue. K split across blockIdx.y.

#define M_TOK 4096
#define DDIM  1024
#define KFLAT 9216

typedef __bf16 bf16x8 __attribute__((ext_vector_type(8)));
typedef float  f32x4  __attribute__((ext_vector_type(4)));
typedef unsigned short u16x4 __attribute__((ext_vector_type(4)));
typedef unsigned short u16x8 __attribute__((ext_vector_type(8)));

#define GLB(p) ((const __attribute__((address_space(1))) void*)(p))
#define LDS(p) ((__attribute__((address_space(3))) void*)(p))

__device__ __forceinline__ unsigned short f2bf(float f) {
    union { float f; uint32_t u; } v; v.f = f;
    uint32_t u = v.u;
    return (unsigned short)((u + 0x7fffu + ((u >> 16) & 1u)) >> 16);  // RNE
}

// ---- fused prep: blocks [0,1024) build W'(flat-K) + bias; [1024,2048) build xs + pmat ----
__global__ __launch_bounds__(256) void prep_dec_kernel(
    const float* __restrict__ x, const float* __restrict__ dec_w,
    const float* __restrict__ dec_b, const float* __restrict__ lw,
    const float* __restrict__ lb, unsigned short* __restrict__ wp,
    float* __restrict__ bw, unsigned short* __restrict__ xs,
    float* __restrict__ pmat)
{
    if (blockIdx.x < 1024) {
        // ---- W-prep: wp[o][l*1024+k] = bf16(dW_l or Wsum), bw[l][o] ----
        int idx = blockIdx.x * 256 + threadIdx.x;     // (o, k/4)
        int o  = idx >> 8;
        int k4 = (idx & 255) << 2;
        size_t src = (size_t)o * DDIM + k4;
        size_t dstb = (size_t)o * KFLAT + k4;
        float4 acc = make_float4(0.f, 0.f, 0.f, 0.f);
#pragma unroll
        for (int j = 0; j < 8; ++j) {
            const float4 a = *(const float4*)(lw + (size_t)(2*j)   * DDIM*DDIM + src);
            const float4 b = *(const float4*)(lw + (size_t)(2*j+1) * DDIM*DDIM + src);
            u16x4 d;
            d[0] = f2bf(a.x - b.x); d[1] = f2bf(a.y - b.y);
            d[2] = f2bf(a.z - b.z); d[3] = f2bf(a.w - b.w);
            *(u16x4*)(wp + dstb + (size_t)j * DDIM) = d;
            acc.x += b.x; acc.y += b.y; acc.z += b.z; acc.w += b.w;
        }
        u16x4 s;
        s[0] = f2bf(acc.x); s[1] = f2bf(acc.y); s[2] = f2bf(acc.z); s[3] = f2bf(acc.w);
        *(u16x4*)(wp + dstb + (size_t)8 * DDIM) = s;
        if ((idx & 255) == 0) {
            float sb = 0.f;
#pragma unroll
            for (int j = 0; j < 8; ++j) {
                float ba = lb[(2*j) * DDIM + o];
                float bb = lb[(2*j+1) * DDIM + o];
                bw[j * DDIM + o] = ba - bb;
                sb += bb;
            }
            bw[8 * DDIM + o] = sb;
        }
    } else {
        // ---- dec: per-token wave: 8 sigmoids, write 9 scaled bf16 copies (flat-K) ----
        int m    = (blockIdx.x - 1024) * 4 + (threadIdx.x >> 6);
        int lane = threadIdx.x & 63;
        const float* xr = x + (size_t)m * DDIM + lane * 16;
        float xv[16];
        *(float4*)&xv[0]  = *(const float4*)(xr + 0);
        *(float4*)&xv[4]  = *(const float4*)(xr + 4);
        *(float4*)&xv[8]  = *(const float4*)(xr + 8);
        *(float4*)&xv[12] = *(const float4*)(xr + 12);
        float s[8];
#pragma unroll
        for (int j = 0; j < 8; ++j) {
            const float* wr = dec_w + (size_t)(7 + j) * DDIM + lane * 16;
            float a = 0.f;
#pragma unroll
            for (int i = 0; i < 16; i += 4) {
                float4 wv = *(const float4*)(wr + i);
                a = fmaf(xv[i], wv.x, fmaf(xv[i+1], wv.y, fmaf(xv[i+2], wv.z, fmaf(xv[i+3], wv.w, a))));
            }
            s[j] = a;
        }
#pragma unroll
        for (int j = 0; j < 8; ++j)
#pragma unroll
            for (int off = 32; off > 0; off >>= 1)
                s[j] += __shfl_xor(s[j], off);
        float p[8];
#pragma unroll
        for (int j = 0; j < 8; ++j)
            p[j] = 1.0f / (1.0f + expf(-(s[j] + dec_b[7 + j])));
        if (lane == 0) {
#pragma unroll
            for (int j = 0; j < 8; ++j)
                pmat[(size_t)m * 8 + j] = p[j];
        }
#pragma unroll
        for (int j = 0; j < 9; ++j) {
            float pj = (j < 8) ? p[j] : 1.0f;
            unsigned short* dst = xs + (size_t)m * KFLAT + j * DDIM + lane * 16;
#pragma unroll
            for (int c = 0; c < 2; ++c) {
                u16x8 o;
#pragma unroll
                for (int e = 0; e < 8; ++e) o[e] = f2bf(pj * xv[c * 8 + e]);
                *(u16x8*)(dst + c * 8) = o;
            }
        }
    }
}

// -------- tree_gemm3: flat GEMM K=9216, 128x128 tile, BK=32, k-split, 4 blk/CU --------
__global__ __launch_bounds__(256, 4) void tree_gemm3(
    const unsigned short* __restrict__ xs,   // [4096][9216] bf16
    const unsigned short* __restrict__ wp,   // [1024][9216] bf16
    const float* __restrict__ bw,            // [9][1024]
    const float* __restrict__ pmat,          // [4096][8]
    float* __restrict__ out,                 // [4096][1024]
    float* __restrict__ parts,               // [ksplit-1][4096][1024]
    int KG)                                  // K per group (9216/ksplit)
{
    __shared__ __align__(16) unsigned short Asm[2][128 * 32];
    __shared__ __align__(16) unsigned short Bsm[2][128 * 32];

    const int tid  = threadIdx.x;
    const int lane = tid & 63;
    const int w    = tid >> 6;
    const int wm   = w >> 1, wn = w & 1;
    // XCD mt-band swizzle: XCD = bx%8 owns mt in [xcd*4, xcd*4+4), all 8 nt.
    const int bx   = blockIdx.x;             // 0..255
    const int xcd  = bx & 7;
    const int ii   = bx >> 3;                // 0..31
    const int mt   = xcd * 4 + (ii >> 3);
    const int nt   = ii & 7;
    const int m0   = mt * 128, n0 = nt * 128;
    const int g    = blockIdx.y;
    const int k0   = g * KG;
    const int ra   = lane & 15;
    const int kb   = (lane >> 4) * 8;

    f32x4 acc[4][4] = {};

    auto stage = [&](int buf, int t) {
#pragma unroll
        for (int c = 0; c < 2; ++c) {
            int row = w * 32 + c * 16 + (lane >> 2);
            int ke  = k0 + t * 32 + (lane & 3) * 8;
            const unsigned short* ga = xs + (size_t)(m0 + row) * KFLAT + ke;
            __builtin_amdgcn_global_load_lds(GLB(ga), LDS(&Asm[buf][w * 1024 + c * 512]), 16, 0, 0);
            const unsigned short* gb = wp + (size_t)(n0 + row) * KFLAT + ke;
            __builtin_amdgcn_global_load_lds(GLB(gb), LDS(&Bsm[buf][w * 1024 + c * 512]), 16, 0, 0);
        }
    };

    const int TOT = KG >> 5;            // 72 (ksplit4) or 96 (ksplit3)
    stage(0, 0);
    __syncthreads();
    int cur = 0;
    for (int t = 0; t < TOT; ++t) {
        if (t + 1 < TOT) stage(cur ^ 1, t + 1);

        bf16x8 av[4], bv[4];
#pragma unroll
        for (int i = 0; i < 4; ++i)
            av[i] = *(const bf16x8*)&Asm[cur][(wm * 64 + i * 16 + ra) * 32 + kb];
#pragma unroll
        for (int j = 0; j < 4; ++j)
            bv[j] = *(const bf16x8*)&Bsm[cur][(wn * 64 + j * 16 + ra) * 32 + kb];
#pragma unroll
        for (int i = 0; i < 4; ++i)
#pragma unroll
            for (int j = 0; j < 4; ++j)
                acc[i][j] = __builtin_amdgcn_mfma_f32_16x16x32_bf16(av[i], bv[j], acc[i][j], 0, 0, 0);

        __syncthreads();
        cur ^= 1;
    }

    // ---- epilogue: group 0 adds bias  sum_{l<8} p_l*bw[l][col] + bw[8][col] ----
    // bw tile for this block's 128 cols cached in LDS (reuse Asm; loop ended on barrier,
    // and __syncthreads drains vmcnt so no staging writes are in flight).
    float* bsm = (float*)&Asm[0][0];    // [9][128] floats = 4.5KB
    if (g == 0) {
        for (int idx = tid; idx < 9 * 128; idx += 256)
            bsm[idx] = bw[(idx >> 7) * DDIM + n0 + (idx & 127)];
    }
    __syncthreads();

    float* dst = (g == 0) ? out : parts + (size_t)(g - 1) * M_TOK * DDIM;
#pragma unroll
    for (int i = 0; i < 4; ++i)
#pragma unroll
        for (int r = 0; r < 4; ++r) {
            int row = m0 + wm * 64 + i * 16 + (lane >> 4) * 4 + r;
            float4 pa, pb;
            if (g == 0) {
                pa = *(const float4*)(pmat + (size_t)row * 8);
                pb = *(const float4*)(pmat + (size_t)row * 8 + 4);
            }
#pragma unroll
            for (int j = 0; j < 4; ++j) {
                int cl = wn * 64 + j * 16 + ra;
                float v = acc[i][j][r];
                if (g == 0) {
                    v += pa.x * bsm[0 * 128 + cl] + pa.y * bsm[1 * 128 + cl]
                       + pa.z * bsm[2 * 128 + cl] + pa.w * bsm[3 * 128 + cl]
                       + pb.x * bsm[4 * 128 + cl] + pb.y * bsm[5 * 128 + cl]
                       + pb.z * bsm[6 * 128 + cl] + pb.w * bsm[7 * 128 + cl]
                       + bsm[8 * 128 + cl];
                }
                dst[(size_t)row * DDIM + n0 + cl] = v;
            }
        }
}

// ---------------- reduce: out += sum of np partials ----------------
__global__ __launch_bounds__(256) void reduce_kernel(
    float* __restrict__ out, const float* __restrict__ parts, int np)
{
    size_t i = (size_t)blockIdx.x * 256 + threadIdx.x;   // float4 index, 1M total
    float4 a = ((const float4*)out)[i];
    for (int p = 0; p < np; ++p) {
        float4 b = ((const float4*)(parts + (size_t)p * M_TOK * DDIM))[i];
        a.x += b.x; a.y += b.y; a.z += b.z; a.w += b.w;
    }
    ((float4*)out)[i] = a;
}

extern "C" void kernel_launch(void* const* d_in, const int* in_sizes, int n_in,
                              void* d_out, int out_size, void* d_ws, size_t ws_size,
                              hipStream_t stream) {
    (void)in_sizes; (void)n_in; (void)out_size;
    const float* x     = (const float*)d_in[0];
    const float* dec_w = (const float*)d_in[1];
    const float* dec_b = (const float*)d_in[2];
    const float* lw    = (const float*)d_in[3];
    const float* lb    = (const float*)d_in[4];
    float* out = (float*)d_out;
    uint8_t* w8 = (uint8_t*)d_ws;

    // layout: xs 72MiB | wp 18MiB | bw 36KiB | pmat 128KiB | parts (ks-1)*16MiB
    unsigned short* xs   = (unsigned short*)(w8);
    unsigned short* wp   = (unsigned short*)(w8 + 75497472);
    float*          bw   = (float*)(w8 + 94371840);
    float*          pmat = (float*)(w8 + 94408704);
    float*          parts= (float*)(w8 + 94539776);
    const size_t NEED3 = 94539776 + 2ull * 16777216;   // 128094208 (proven fits)
    const size_t NEED4 = 94539776 + 3ull * 16777216;   // 144871424

    int ks = (ws_size >= NEED4) ? 4 : (ws_size >= NEED3) ? 3 : 0;
    if (!ks) return;  // cannot happen on this harness (round-2 ran with NEED3)

    prep_dec_kernel<<<2048, 256, 0, stream>>>(x, dec_w, dec_b, lw, lb, wp, bw, xs, pmat);
    tree_gemm3<<<dim3(256, ks), 256, 0, stream>>>(xs, wp, bw, pmat, out, parts, KFLAT / ks);
    reduce_kernel<<<4096, 256, 0, stream>>>(out, parts, ks - 1);
}

// Round 5
// 129.959 us; speedup vs baseline: 1.1944x; 1.1531x over previous
//
#include <hip/hip_runtime.h>
#include <stdint.h>

// DecisionTree: out = sum_l p_l * (x @ W_l^T + b_l), p from bottom-layer sigmoids.
// Pair-folded + A-prescaled: ONE flat GEMM A[4096x9216] @ B[1024x9216]^T.
// tree_gemm4: 256x256 tile, BK=64, 8-phase counted-vmcnt schedule (T2+T3+T4+T5).
// RACE FIX vs round 4: every counted vmcnt sits IMMEDIATELY BEFORE a barrier
// (vmcnt is per-wave; only wait->barrier makes "landed" true chip-wide).

#define M_TOK 4096
#define DDIM  1024
#define KFLAT 9216

typedef __bf16 bf16x8 __attribute__((ext_vector_type(8)));
typedef float  f32x4  __attribute__((ext_vector_type(4)));
typedef unsigned short u16x4 __attribute__((ext_vector_type(4)));
typedef unsigned short u16x8 __attribute__((ext_vector_type(8)));

#define GLB(p) ((const __attribute__((address_space(1))) void*)(p))
#define LDS(p) ((__attribute__((address_space(3))) void*)(p))

__device__ __forceinline__ unsigned short f2bf(float f) {
    union { float f; uint32_t u; } v; v.f = f;
    uint32_t u = v.u;
    return (unsigned short)((u + 0x7fffu + ((u >> 16) & 1u)) >> 16);  // RNE
}

__device__ __forceinline__ bf16x8 asbf(f32x4 v) {
    bf16x8 r; __builtin_memcpy(&r, &v, 16); return r;
}

template<int OFF>
__device__ __forceinline__ f32x4 dsr(uint32_t a) {
    f32x4 r;
    asm volatile("ds_read_b128 %0, %1 offset:%c2" : "=v"(r) : "v"(a), "i"(OFF));
    return r;
}

// ---- fused prep: blocks [0,1024) build W'(flat-K) + bias; [1024,2048) build xs + pmat ----
__global__ __launch_bounds__(256) void prep_dec_kernel(
    const float* __restrict__ x, const float* __restrict__ dec_w,
    const float* __restrict__ dec_b, const float* __restrict__ lw,
    const float* __restrict__ lb, unsigned short* __restrict__ wp,
    float* __restrict__ bw, unsigned short* __restrict__ xs,
    float* __restrict__ pmat)
{
    if (blockIdx.x < 1024) {
        int idx = blockIdx.x * 256 + threadIdx.x;     // (o, k/4)
        int o  = idx >> 8;
        int k4 = (idx & 255) << 2;
        size_t src = (size_t)o * DDIM + k4;
        size_t dstb = (size_t)o * KFLAT + k4;
        float4 acc = make_float4(0.f, 0.f, 0.f, 0.f);
#pragma unroll
        for (int j = 0; j < 8; ++j) {
            const float4 a = *(const float4*)(lw + (size_t)(2*j)   * DDIM*DDIM + src);
            const float4 b = *(const float4*)(lw + (size_t)(2*j+1) * DDIM*DDIM + src);
            u16x4 d;
            d[0] = f2bf(a.x - b.x); d[1] = f2bf(a.y - b.y);
            d[2] = f2bf(a.z - b.z); d[3] = f2bf(a.w - b.w);
            *(u16x4*)(wp + dstb + (size_t)j * DDIM) = d;
            acc.x += b.x; acc.y += b.y; acc.z += b.z; acc.w += b.w;
        }
        u16x4 s;
        s[0] = f2bf(acc.x); s[1] = f2bf(acc.y); s[2] = f2bf(acc.z); s[3] = f2bf(acc.w);
        *(u16x4*)(wp + dstb + (size_t)8 * DDIM) = s;
        if ((idx & 255) == 0) {
            float sb = 0.f;
#pragma unroll
            for (int j = 0; j < 8; ++j) {
                float ba = lb[(2*j) * DDIM + o];
                float bb = lb[(2*j+1) * DDIM + o];
                bw[j * DDIM + o] = ba - bb;
                sb += bb;
            }
            bw[8 * DDIM + o] = sb;
        }
    } else {
        int m    = (blockIdx.x - 1024) * 4 + (threadIdx.x >> 6);
        int lane = threadIdx.x & 63;
        const float* xr = x + (size_t)m * DDIM + lane * 16;
        float xv[16];
        *(float4*)&xv[0]  = *(const float4*)(xr + 0);
        *(float4*)&xv[4]  = *(const float4*)(xr + 4);
        *(float4*)&xv[8]  = *(const float4*)(xr + 8);
        *(float4*)&xv[12] = *(const float4*)(xr + 12);
        float s[8];
#pragma unroll
        for (int j = 0; j < 8; ++j) {
            const float* wr = dec_w + (size_t)(7 + j) * DDIM + lane * 16;
            float a = 0.f;
#pragma unroll
            for (int i = 0; i < 16; i += 4) {
                float4 wv = *(const float4*)(wr + i);
                a = fmaf(xv[i], wv.x, fmaf(xv[i+1], wv.y, fmaf(xv[i+2], wv.z, fmaf(xv[i+3], wv.w, a))));
            }
            s[j] = a;
        }
#pragma unroll
        for (int j = 0; j < 8; ++j)
#pragma unroll
            for (int off = 32; off > 0; off >>= 1)
                s[j] += __shfl_xor(s[j], off);
        float p[8];
#pragma unroll
        for (int j = 0; j < 8; ++j)
            p[j] = 1.0f / (1.0f + expf(-(s[j] + dec_b[7 + j])));
        if (lane == 0) {
#pragma unroll
            for (int j = 0; j < 8; ++j)
                pmat[(size_t)m * 8 + j] = p[j];
        }
#pragma unroll
        for (int j = 0; j < 9; ++j) {
            float pj = (j < 8) ? p[j] : 1.0f;
            unsigned short* dst = xs + (size_t)m * KFLAT + j * DDIM + lane * 16;
#pragma unroll
            for (int c = 0; c < 2; ++c) {
                u16x8 o;
#pragma unroll
                for (int e = 0; e < 8; ++e) o[e] = f2bf(pj * xv[c * 8 + e]);
                *(u16x8*)(dst + c * 8) = o;
            }
        }
    }
}

// ================= tree_gemm4: 256^2 8-phase schedule =================
// LDS: A0[0,32K) A1[32K,64K) B0[64K,96K) B1[96K,128K). Tile = 256 rows x 64 k bf16,
// row = 128B. Swizzle per row r of the 128B: half-bit(b6) ^= r&1; 16B-chunk rotated
// by (r>>1)&3. Linear global_load_lds dest + inverse-permuted global src + swizzled
// ds_read addr => both sides conflict-free. (Layout validated in round 4, call 1.)

#define WAITV4 asm volatile("s_waitcnt vmcnt(4)" ::: "memory")
#define WAITV0 asm volatile("s_waitcnt vmcnt(0)" ::: "memory")
#define BARR   __builtin_amdgcn_s_barrier()
#define LGKM0  do { asm volatile("s_waitcnt lgkmcnt(0)" ::: "memory"); \
                    __builtin_amdgcn_sched_barrier(0); } while(0)

#define READ_AV(q, b) do { \
    av[0][0] = dsr<(b)*32768 + (2*(q)+0)*2048>(baseA0); \
    av[0][1] = dsr<(b)*32768 + (2*(q)+0)*2048>(baseA1); \
    av[1][0] = dsr<(b)*32768 + (2*(q)+1)*2048>(baseA0); \
    av[1][1] = dsr<(b)*32768 + (2*(q)+1)*2048>(baseA1); \
} while(0)

#define READ_BV(b) do { \
    bv[0][0] = dsr<(b)*32768 + 0*2048>(baseB0); bv[0][1] = dsr<(b)*32768 + 0*2048>(baseB1); \
    bv[1][0] = dsr<(b)*32768 + 1*2048>(baseB0); bv[1][1] = dsr<(b)*32768 + 1*2048>(baseB1); \
    bv[2][0] = dsr<(b)*32768 + 2*2048>(baseB0); bv[2][1] = dsr<(b)*32768 + 2*2048>(baseB1); \
    bv[3][0] = dsr<(b)*32768 + 3*2048>(baseB0); bv[3][1] = dsr<(b)*32768 + 3*2048>(baseB1); \
} while(0)

#define MFMA_Q(q) do { \
    __builtin_amdgcn_s_setprio(1); \
    _Pragma("unroll") \
    for (int mfl = 0; mfl < 2; ++mfl) { \
        _Pragma("unroll") \
        for (int j = 0; j < 4; ++j) { \
            acc[2*(q)+mfl][j] = __builtin_amdgcn_mfma_f32_16x16x32_bf16(asbf(av[mfl][0]), asbf(bv[j][0]), acc[2*(q)+mfl][j], 0, 0, 0); \
            acc[2*(q)+mfl][j] = __builtin_amdgcn_mfma_f32_16x16x32_bf16(asbf(av[mfl][1]), asbf(bv[j][1]), acc[2*(q)+mfl][j], 0, 0, 0); \
        } \
    } \
    __builtin_amdgcn_s_setprio(0); \
} while(0)

__global__ __launch_bounds__(512, 2) void tree_gemm4(
    const unsigned short* __restrict__ xs,   // [4096][9216] bf16
    const unsigned short* __restrict__ wp,   // [1024][9216] bf16
    float* __restrict__ out,                 // [4096][1024] (group 0, no bias yet)
    float* __restrict__ parts,               // [ks-1][4096][1024]
    int KG)                                  // K per group, multiple of 128
{
    extern __shared__ char smem[];
    const int tid  = threadIdx.x;
    const int lane = tid & 63;
    const int w    = tid >> 6;               // 0..7
    const int wm   = w >> 2, wn = w & 3;     // 2M x 4N waves
    const int ra   = lane & 15;
    const int g16  = lane >> 4;              // 0..3

    // XCD band swizzle: 64 x-blocks; xcd = bx&7 gets 8 blocks = 8 mt x 1 nt.
    const int bx  = blockIdx.x;
    const int xcd = bx & 7, ii = bx >> 3;
    const int nt  = xcd >> 1;
    const int mt  = (xcd & 1) * 8 + ii;
    const int m0  = mt * 256, n0 = nt * 256;
    const int g   = blockIdx.y;
    const int k0  = g * KG;
    const int NI  = KG >> 7;                 // iterations (2 K-tiles each)

    uint32_t sbase = (uint32_t)(uintptr_t)(__attribute__((address_space(3))) char*)smem;

    // read-side swizzled column bytes (lane-const)
    const uint32_t colb0 = (uint32_t)(((ra & 1) << 6) | (((g16 + ((ra >> 1) & 3)) & 3) << 4));
    const uint32_t colb1 = colb0 ^ 64;
    const uint32_t baseA0 = sbase + wm * 16384 + ra * 128 + colb0;
    const uint32_t baseA1 = sbase + wm * 16384 + ra * 128 + colb1;
    const uint32_t baseB0 = sbase + 65536 + wn * 8192 + ra * 128 + colb0;
    const uint32_t baseB1 = sbase + 65536 + wn * 8192 + ra * 128 + colb1;

    // staging lane-consts: linear LDS dest <- inverse-swizzled global source chunk
    const int sh  = ((lane >> 2) ^ (lane >> 3)) & 1;
    const int sc  = ((lane & 3) - ((lane >> 4) & 3)) & 3;
    const int kel = sh * 32 + sc * 8;        // element offset within 64-k window
    const int rA  = w * 8 + (lane >> 3);     // row within half-tile

    auto stageA = [&](int buf, int tt, int hh) {
        const unsigned short* s0 = xs + (size_t)(m0 + hh * 128 + rA) * KFLAT + (k0 + tt * 64 + kel);
        char* d0 = smem + buf * 32768 + hh * 16384 + w * 1024;
        __builtin_amdgcn_global_load_lds(GLB(s0), LDS(d0), 16, 0, 0);
        __builtin_amdgcn_global_load_lds(GLB(s0 + (size_t)64 * KFLAT), LDS(d0 + 8192), 16, 0, 0);
    };
    auto stageB = [&](int buf, int tt, int hh) {
        const unsigned short* s0 = wp + (size_t)(n0 + hh * 128 + rA) * KFLAT + (k0 + tt * 64 + kel);
        char* d0 = smem + 65536 + buf * 32768 + hh * 16384 + w * 1024;
        __builtin_amdgcn_global_load_lds(GLB(s0), LDS(d0), 16, 0, 0);
        __builtin_amdgcn_global_load_lds(GLB(s0 + (size_t)64 * KFLAT), LDS(d0 + 8192), 16, 0, 0);
    };

    f32x4 acc[8][4] = {};
    f32x4 av[2][2], bv[4][2];

    // ---- prologue: A0(0), B0(0), B1(1) = 12 loads.
    // vmcnt(4)+barrier => tile-0 landed chip-wide; B1(1) (4 newest) may fly.
    stageA(0, 0, 0); stageA(0, 0, 1);
    stageB(0, 0, 0); stageB(0, 0, 1);
    stageB(1, 1, 0); stageB(1, 1, 1);
    WAITV4;
    BARR;

    for (int i = 0; i < NI; ++i) {
        const int t = 2 * i;
        const bool on = (i + 1 < NI);

        // ======== K-tile t (buffers 0) ========
        // ph0: reads + stage A1(t+1) both halves
        READ_BV(0); READ_AV(0, 0);
        stageA(1, t + 1, 0); stageA(1, t + 1, 1);
        BARR; LGKM0; MFMA_Q(0); BARR;
        // ph1
        READ_AV(1, 0);
        if (on) stageB(0, t + 2, 0);
        BARR; LGKM0; MFMA_Q(1); BARR;
        // ph2
        READ_AV(2, 0);
        if (on) stageB(0, t + 2, 1);
        BARR; LGKM0; MFMA_Q(2); BARR;
        // ph3 — WAIT X before trailing barrier:
        // outstanding = B1(t+1):4 | A1(t+1):4 | B0(t+2):4(newest) -> vmcnt(4)
        // protects everything phases 4-7 read. Last iter: only A1 flying -> vmcnt(0).
        READ_AV(3, 0);
        BARR; LGKM0; MFMA_Q(3);
        if (on) { WAITV4; } else { WAITV0; }
        BARR;

        // ======== K-tile t+1 (buffers 1) ========
        // ph4: reads + stage A0(t+2) both halves
        READ_BV(1); READ_AV(0, 1);
        if (on) { stageA(0, t + 2, 0); stageA(0, t + 2, 1); }
        BARR; LGKM0; MFMA_Q(0); BARR;
        // ph5
        READ_AV(1, 1);
        if (on) stageB(1, t + 3, 0);
        BARR; LGKM0; MFMA_Q(1); BARR;
        // ph6
        READ_AV(2, 1);
        if (on) stageB(1, t + 3, 1);
        BARR; LGKM0; MFMA_Q(2); BARR;
        // ph7 — WAIT Y before trailing barrier:
        // outstanding = B0(t+2):4 | A0(t+2):4 | B1(t+3):4(newest) -> vmcnt(4)
        // protects next iteration's ph0 reads (A0,B0 of tile t+2).
        READ_AV(3, 1);
        BARR; LGKM0; MFMA_Q(3);
        if (on) WAITV4;
        BARR;
    }

    // epilogue: plain store (bias added in reduce)
    float* dst = (g == 0) ? out : parts + (size_t)(g - 1) * M_TOK * DDIM;
#pragma unroll
    for (int mf = 0; mf < 8; ++mf)
#pragma unroll
        for (int e = 0; e < 4; ++e) {
            int row = m0 + wm * 128 + mf * 16 + g16 * 4 + e;
#pragma unroll
            for (int j = 0; j < 4; ++j)
                dst[(size_t)row * DDIM + n0 + wn * 64 + j * 16 + ra] = acc[mf][j][e];
        }
}

// ---------------- reduce2: out = out + sum parts + bias(p . bw) ----------------
__global__ __launch_bounds__(256) void reduce2_kernel(
    float* __restrict__ out, const float* __restrict__ parts,
    const float* __restrict__ pmat, const float* __restrict__ bw, int np)
{
    size_t i = (size_t)blockIdx.x * 256 + threadIdx.x;   // float4 idx, 1M total
    int m   = (int)(i >> 8);
    int col = (int)(i & 255) * 4;
    float4 a = ((const float4*)out)[i];
    for (int p = 0; p < np; ++p) {
        float4 b = ((const float4*)(parts + (size_t)p * M_TOK * DDIM))[i];
        a.x += b.x; a.y += b.y; a.z += b.z; a.w += b.w;
    }
    float4 pa = *(const float4*)(pmat + (size_t)m * 8);
    float4 pb = *(const float4*)(pmat + (size_t)m * 8 + 4);
    float4 bias = *(const float4*)(bw + 8 * DDIM + col);
#pragma unroll
    for (int l = 0; l < 8; ++l) {
        float pl = (l < 4) ? ((const float*)&pa)[l] : ((const float*)&pb)[l - 4];
        float4 bl = *(const float4*)(bw + l * DDIM + col);
        bias.x = fmaf(pl, bl.x, bias.x); bias.y = fmaf(pl, bl.y, bias.y);
        bias.z = fmaf(pl, bl.z, bias.z); bias.w = fmaf(pl, bl.w, bias.w);
    }
    a.x += bias.x; a.y += bias.y; a.z += bias.z; a.w += bias.w;
    ((float4*)out)[i] = a;
}

// ================= fallback (round-3 proven): tree_gemm3 + reduce =================
__global__ __launch_bounds__(256, 4) void tree_gemm3(
    const unsigned short* __restrict__ xs, const unsigned short* __restrict__ wp,
    const float* __restrict__ bw, const float* __restrict__ pmat,
    float* __restrict__ out, float* __restrict__ parts, int KG)
{
    __shared__ __align__(16) unsigned short Asm[2][128 * 32];
    __shared__ __align__(16) unsigned short Bsm[2][128 * 32];
    const int tid  = threadIdx.x;
    const int lane = tid & 63;
    const int w    = tid >> 6;
    const int wm   = w >> 1, wn = w & 1;
    const int bx   = blockIdx.x;
    const int xcd  = bx & 7;
    const int ii   = bx >> 3;
    const int mt   = xcd * 4 + (ii >> 3);
    const int nt   = ii & 7;
    const int m0   = mt * 128, n0 = nt * 128;
    const int g    = blockIdx.y;
    const int k0   = g * KG;
    const int ra   = lane & 15;
    const int kb   = (lane >> 4) * 8;
    f32x4 acc[4][4] = {};
    auto stage = [&](int buf, int t) {
#pragma unroll
        for (int c = 0; c < 2; ++c) {
            int row = w * 32 + c * 16 + (lane >> 2);
            int ke  = k0 + t * 32 + (lane & 3) * 8;
            const unsigned short* ga = xs + (size_t)(m0 + row) * KFLAT + ke;
            __builtin_amdgcn_global_load_lds(GLB(ga), LDS(&Asm[buf][w * 1024 + c * 512]), 16, 0, 0);
            const unsigned short* gb = wp + (size_t)(n0 + row) * KFLAT + ke;
            __builtin_amdgcn_global_load_lds(GLB(gb), LDS(&Bsm[buf][w * 1024 + c * 512]), 16, 0, 0);
        }
    };
    const int TOT = KG >> 5;
    stage(0, 0);
    __syncthreads();
    int cur = 0;
    for (int t = 0; t < TOT; ++t) {
        if (t + 1 < TOT) stage(cur ^ 1, t + 1);
        bf16x8 av2[4], bv2[4];
#pragma unroll
        for (int i2 = 0; i2 < 4; ++i2)
            av2[i2] = *(const bf16x8*)&Asm[cur][(wm * 64 + i2 * 16 + ra) * 32 + kb];
#pragma unroll
        for (int j = 0; j < 4; ++j)
            bv2[j] = *(const bf16x8*)&Bsm[cur][(wn * 64 + j * 16 + ra) * 32 + kb];
#pragma unroll
        for (int i2 = 0; i2 < 4; ++i2)
#pragma unroll
            for (int j = 0; j < 4; ++j)
                acc[i2][j] = __builtin_amdgcn_mfma_f32_16x16x32_bf16(av2[i2], bv2[j], acc[i2][j], 0, 0, 0);
        __syncthreads();
        cur ^= 1;
    }
    float* bsm = (float*)&Asm[0][0];
    if (g == 0) {
        for (int idx = tid; idx < 9 * 128; idx += 256)
            bsm[idx] = bw[(idx >> 7) * DDIM + n0 + (idx & 127)];
    }
    __syncthreads();
    float* dst = (g == 0) ? out : parts + (size_t)(g - 1) * M_TOK * DDIM;
#pragma unroll
    for (int i2 = 0; i2 < 4; ++i2)
#pragma unroll
        for (int r = 0; r < 4; ++r) {
            int row = m0 + wm * 64 + i2 * 16 + (lane >> 4) * 4 + r;
            float4 pa, pb;
            if (g == 0) {
                pa = *(const float4*)(pmat + (size_t)row * 8);
                pb = *(const float4*)(pmat + (size_t)row * 8 + 4);
            }
#pragma unroll
            for (int j = 0; j < 4; ++j) {
                int cl = wn * 64 + j * 16 + ra;
                float v = acc[i2][j][r];
                if (g == 0) {
                    v += pa.x * bsm[0 * 128 + cl] + pa.y * bsm[1 * 128 + cl]
                       + pa.z * bsm[2 * 128 + cl] + pa.w * bsm[3 * 128 + cl]
                       + pb.x * bsm[4 * 128 + cl] + pb.y * bsm[5 * 128 + cl]
                       + pb.z * bsm[6 * 128 + cl] + pb.w * bsm[7 * 128 + cl]
                       + bsm[8 * 128 + cl];
                }
                dst[(size_t)row * DDIM + n0 + cl] = v;
            }
        }
}

__global__ __launch_bounds__(256) void reduce_kernel(
    float* __restrict__ out, const float* __restrict__ parts, int np)
{
    size_t i = (size_t)blockIdx.x * 256 + threadIdx.x;
    float4 a = ((const float4*)out)[i];
    for (int p = 0; p < np; ++p) {
        float4 b = ((const float4*)(parts + (size_t)p * M_TOK * DDIM))[i];
        a.x += b.x; a.y += b.y; a.z += b.z; a.w += b.w;
    }
    ((float4*)out)[i] = a;
}

extern "C" void kernel_launch(void* const* d_in, const int* in_sizes, int n_in,
                              void* d_out, int out_size, void* d_ws, size_t ws_size,
                              hipStream_t stream) {
    (void)in_sizes; (void)n_in; (void)out_size;
    const float* x     = (const float*)d_in[0];
    const float* dec_w = (const float*)d_in[1];
    const float* dec_b = (const float*)d_in[2];
    const float* lw    = (const float*)d_in[3];
    const float* lb    = (const float*)d_in[4];
    float* out = (float*)d_out;
    uint8_t* w8 = (uint8_t*)d_ws;

    // layout: xs 72MiB | wp 18MiB | bw 36KiB | pmat 128KiB | parts (ks-1)*16MiB
    unsigned short* xs   = (unsigned short*)(w8);
    unsigned short* wp   = (unsigned short*)(w8 + 75497472);
    float*          bw   = (float*)(w8 + 94371840);
    float*          pmat = (float*)(w8 + 94408704);
    float*          parts= (float*)(w8 + 94539776);
    const size_t NEED3 = 94539776 + 2ull * 16777216;
    const size_t NEED4 = 94539776 + 3ull * 16777216;

    int ks = (ws_size >= NEED4) ? 4 : (ws_size >= NEED3) ? 3 : 0;
    if (!ks) return;

    prep_dec_kernel<<<2048, 256, 0, stream>>>(x, dec_w, dec_b, lw, lb, wp, bw, xs, pmat);

    hipError_t e = hipFuncSetAttribute(
        reinterpret_cast<const void*>(tree_gemm4),
        hipFuncAttributeMaxDynamicSharedMemorySize, 131072);
    if (e == hipSuccess) {
        tree_gemm4<<<dim3(64, ks), 512, 131072, stream>>>(xs, wp, out, parts, KFLAT / ks);
        reduce2_kernel<<<4096, 256, 0, stream>>>(out, parts, pmat, bw, ks - 1);
    } else {
        tree_gemm3<<<dim3(256, ks), 256, 0, stream>>>(xs, wp, bw, pmat, out, parts, KFLAT / ks);
        reduce_kernel<<<4096, 256, 0, stream>>>(out, parts, ks - 1);
    }
}

// Round 6
// 127.355 us; speedup vs baseline: 1.2189x; 1.0205x over previous
//
#include <hip/hip_runtime.h>
#include <stdint.h>

// DecisionTree: out = sum_l p_l * (x @ W_l^T + b_l), p from bottom-layer sigmoids.
// Pair-folded + A-prescaled: ONE flat GEMM A[4096x9216] @ B[1024x9216]^T.
// tree_gemm4: 256x256 tile, BK=64, 8-phase counted-vmcnt schedule (T2+T3+T4+T5).
// Round 6: G4 XOR swizzle (byte ^= (row&7)<<4) replaces rotate swizzle —
// round-5 counters showed exactly +4 conflict cycles per ds_read_b128.

#define M_TOK 4096
#define DDIM  1024
#define KFLAT 9216

typedef __bf16 bf16x8 __attribute__((ext_vector_type(8)));
typedef float  f32x4  __attribute__((ext_vector_type(4)));
typedef unsigned short u16x4 __attribute__((ext_vector_type(4)));
typedef unsigned short u16x8 __attribute__((ext_vector_type(8)));

#define GLB(p) ((const __attribute__((address_space(1))) void*)(p))
#define LDS(p) ((__attribute__((address_space(3))) void*)(p))

__device__ __forceinline__ unsigned short f2bf(float f) {
    union { float f; uint32_t u; } v; v.f = f;
    uint32_t u = v.u;
    return (unsigned short)((u + 0x7fffu + ((u >> 16) & 1u)) >> 16);  // RNE
}

__device__ __forceinline__ bf16x8 asbf(f32x4 v) {
    bf16x8 r; __builtin_memcpy(&r, &v, 16); return r;
}

template<int OFF>
__device__ __forceinline__ f32x4 dsr(uint32_t a) {
    f32x4 r;
    asm volatile("ds_read_b128 %0, %1 offset:%c2" : "=v"(r) : "v"(a), "i"(OFF));
    return r;
}

// ---- fused prep: blocks [0,1024) build W'(flat-K) + bias; [1024,2048) build xs + pmat ----
__global__ __launch_bounds__(256) void prep_dec_kernel(
    const float* __restrict__ x, const float* __restrict__ dec_w,
    const float* __restrict__ dec_b, const float* __restrict__ lw,
    const float* __restrict__ lb, unsigned short* __restrict__ wp,
    float* __restrict__ bw, unsigned short* __restrict__ xs,
    float* __restrict__ pmat)
{
    if (blockIdx.x < 1024) {
        int idx = blockIdx.x * 256 + threadIdx.x;     // (o, k/4)
        int o  = idx >> 8;
        int k4 = (idx & 255) << 2;
        size_t src = (size_t)o * DDIM + k4;
        size_t dstb = (size_t)o * KFLAT + k4;
        float4 acc = make_float4(0.f, 0.f, 0.f, 0.f);
#pragma unroll
        for (int j = 0; j < 8; ++j) {
            const float4 a = *(const float4*)(lw + (size_t)(2*j)   * DDIM*DDIM + src);
            const float4 b = *(const float4*)(lw + (size_t)(2*j+1) * DDIM*DDIM + src);
            u16x4 d;
            d[0] = f2bf(a.x - b.x); d[1] = f2bf(a.y - b.y);
            d[2] = f2bf(a.z - b.z); d[3] = f2bf(a.w - b.w);
            *(u16x4*)(wp + dstb + (size_t)j * DDIM) = d;
            acc.x += b.x; acc.y += b.y; acc.z += b.z; acc.w += b.w;
        }
        u16x4 s;
        s[0] = f2bf(acc.x); s[1] = f2bf(acc.y); s[2] = f2bf(acc.z); s[3] = f2bf(acc.w);
        *(u16x4*)(wp + dstb + (size_t)8 * DDIM) = s;
        if ((idx & 255) == 0) {
            float sb = 0.f;
#pragma unroll
            for (int j = 0; j < 8; ++j) {
                float ba = lb[(2*j) * DDIM + o];
                float bb = lb[(2*j+1) * DDIM + o];
                bw[j * DDIM + o] = ba - bb;
                sb += bb;
            }
            bw[8 * DDIM + o] = sb;
        }
    } else {
        int m    = (blockIdx.x - 1024) * 4 + (threadIdx.x >> 6);
        int lane = threadIdx.x & 63;
        const float* xr = x + (size_t)m * DDIM + lane * 16;
        float xv[16];
        *(float4*)&xv[0]  = *(const float4*)(xr + 0);
        *(float4*)&xv[4]  = *(const float4*)(xr + 4);
        *(float4*)&xv[8]  = *(const float4*)(xr + 8);
        *(float4*)&xv[12] = *(const float4*)(xr + 12);
        float s[8];
#pragma unroll
        for (int j = 0; j < 8; ++j) {
            const float* wr = dec_w + (size_t)(7 + j) * DDIM + lane * 16;
            float a = 0.f;
#pragma unroll
            for (int i = 0; i < 16; i += 4) {
                float4 wv = *(const float4*)(wr + i);
                a = fmaf(xv[i], wv.x, fmaf(xv[i+1], wv.y, fmaf(xv[i+2], wv.z, fmaf(xv[i+3], wv.w, a))));
            }
            s[j] = a;
        }
#pragma unroll
        for (int j = 0; j < 8; ++j)
#pragma unroll
            for (int off = 32; off > 0; off >>= 1)
                s[j] += __shfl_xor(s[j], off);
        float p[8];
#pragma unroll
        for (int j = 0; j < 8; ++j)
            p[j] = 1.0f / (1.0f + expf(-(s[j] + dec_b[7 + j])));
        if (lane == 0) {
#pragma unroll
            for (int j = 0; j < 8; ++j)
                pmat[(size_t)m * 8 + j] = p[j];
        }
#pragma unroll
        for (int j = 0; j < 9; ++j) {
            float pj = (j < 8) ? p[j] : 1.0f;
            unsigned short* dst = xs + (size_t)m * KFLAT + j * DDIM + lane * 16;
#pragma unroll
            for (int c = 0; c < 2; ++c) {
                u16x8 o;
#pragma unroll
                for (int e = 0; e < 8; ++e) o[e] = f2bf(pj * xv[c * 8 + e]);
                *(u16x8*)(dst + c * 8) = o;
            }
        }
    }
}

// ================= tree_gemm4: 256^2 8-phase schedule =================
// LDS: A0[0,32K) A1[32K,64K) B0[64K,96K) B1[96K,128K). Tile = 256 rows x 64 k bf16,
// row = 128B. G4 swizzle: physical byte-in-row = logical ^ ((row&7)<<4).
// Involution: linear global_load_lds dest + inverse-XORed global src chunk +
// XORed ds_read addr. Conflict-verified pattern (guide §6 G4, +89% attn).

#define WAITV4 asm volatile("s_waitcnt vmcnt(4)" ::: "memory")
#define WAITV0 asm volatile("s_waitcnt vmcnt(0)" ::: "memory")
#define BARR   __builtin_amdgcn_s_barrier()
#define LGKM0  do { asm volatile("s_waitcnt lgkmcnt(0)" ::: "memory"); \
                    __builtin_amdgcn_sched_barrier(0); } while(0)

#define READ_AV(q, b) do { \
    av[0][0] = dsr<(b)*32768 + (2*(q)+0)*2048>(baseA0); \
    av[0][1] = dsr<(b)*32768 + (2*(q)+0)*2048>(baseA1); \
    av[1][0] = dsr<(b)*32768 + (2*(q)+1)*2048>(baseA0); \
    av[1][1] = dsr<(b)*32768 + (2*(q)+1)*2048>(baseA1); \
} while(0)

#define READ_BV(b) do { \
    bv[0][0] = dsr<(b)*32768 + 0*2048>(baseB0); bv[0][1] = dsr<(b)*32768 + 0*2048>(baseB1); \
    bv[1][0] = dsr<(b)*32768 + 1*2048>(baseB0); bv[1][1] = dsr<(b)*32768 + 1*2048>(baseB1); \
    bv[2][0] = dsr<(b)*32768 + 2*2048>(baseB0); bv[2][1] = dsr<(b)*32768 + 2*2048>(baseB1); \
    bv[3][0] = dsr<(b)*32768 + 3*2048>(baseB0); bv[3][1] = dsr<(b)*32768 + 3*2048>(baseB1); \
} while(0)

#define MFMA_Q(q) do { \
    __builtin_amdgcn_s_setprio(1); \
    _Pragma("unroll") \
    for (int mfl = 0; mfl < 2; ++mfl) { \
        _Pragma("unroll") \
        for (int j = 0; j < 4; ++j) { \
            acc[2*(q)+mfl][j] = __builtin_amdgcn_mfma_f32_16x16x32_bf16(asbf(av[mfl][0]), asbf(bv[j][0]), acc[2*(q)+mfl][j], 0, 0, 0); \
            acc[2*(q)+mfl][j] = __builtin_amdgcn_mfma_f32_16x16x32_bf16(asbf(av[mfl][1]), asbf(bv[j][1]), acc[2*(q)+mfl][j], 0, 0, 0); \
        } \
    } \
    __builtin_amdgcn_s_setprio(0); \
} while(0)

__global__ __launch_bounds__(512, 2) void tree_gemm4(
    const unsigned short* __restrict__ xs,   // [4096][9216] bf16
    const unsigned short* __restrict__ wp,   // [1024][9216] bf16
    float* __restrict__ out,                 // [4096][1024] (group 0, no bias yet)
    float* __restrict__ parts,               // [ks-1][4096][1024]
    int KG)                                  // K per group, multiple of 128
{
    extern __shared__ char smem[];
    const int tid  = threadIdx.x;
    const int lane = tid & 63;
    const int w    = tid >> 6;               // 0..7
    const int wm   = w >> 2, wn = w & 3;     // 2M x 4N waves
    const int ra   = lane & 15;
    const int g16  = lane >> 4;              // 0..3

    // XCD band swizzle: 64 x-blocks; xcd = bx&7 gets 8 blocks = 8 mt x 1 nt.
    const int bx  = blockIdx.x;
    const int xcd = bx & 7, ii = bx >> 3;
    const int nt  = xcd >> 1;
    const int mt  = (xcd & 1) * 8 + ii;
    const int m0  = mt * 256, n0 = nt * 256;
    const int g   = blockIdx.y;
    const int k0  = g * KG;
    const int NI  = KG >> 7;                 // iterations (2 K-tiles each)

    uint32_t sbase = (uint32_t)(uintptr_t)(__attribute__((address_space(3))) char*)smem;

    // read-side G4-swizzled column bytes: slot = g16 ^ (row&7); row&7 == ra&7
    const uint32_t colb0 = (uint32_t)((g16 ^ (ra & 7)) << 4);
    const uint32_t colb1 = colb0 ^ 64;       // k-half bit XORs through the swizzle
    const uint32_t baseA0 = sbase + wm * 16384 + ra * 128 + colb0;
    const uint32_t baseA1 = sbase + wm * 16384 + ra * 128 + colb1;
    const uint32_t baseB0 = sbase + 65536 + wn * 8192 + ra * 128 + colb0;
    const uint32_t baseB1 = sbase + 65536 + wn * 8192 + ra * 128 + colb1;

    // staging lane-consts: linear LDS dest <- inverse-XORed global source chunk.
    // lane writes physical byte (lane&7)*16 of row w*8 + (lane>>3);
    // logical byte = physical ^ ((row&7)<<4), row&7 = lane>>3.
    const int kel = (((lane & 7) ^ (lane >> 3)) & 7) * 8;  // element offset in 64-k window
    const int rA  = w * 8 + (lane >> 3);     // row within half-tile

    auto stageA = [&](int buf, int tt, int hh) {
        const unsigned short* s0 = xs + (size_t)(m0 + hh * 128 + rA) * KFLAT + (k0 + tt * 64 + kel);
        char* d0 = smem + buf * 32768 + hh * 16384 + w * 1024;
        __builtin_amdgcn_global_load_lds(GLB(s0), LDS(d0), 16, 0, 0);
        __builtin_amdgcn_global_load_lds(GLB(s0 + (size_t)64 * KFLAT), LDS(d0 + 8192), 16, 0, 0);
    };
    auto stageB = [&](int buf, int tt, int hh) {
        const unsigned short* s0 = wp + (size_t)(n0 + hh * 128 + rA) * KFLAT + (k0 + tt * 64 + kel);
        char* d0 = smem + 65536 + buf * 32768 + hh * 16384 + w * 1024;
        __builtin_amdgcn_global_load_lds(GLB(s0), LDS(d0), 16, 0, 0);
        __builtin_amdgcn_global_load_lds(GLB(s0 + (size_t)64 * KFLAT), LDS(d0 + 8192), 16, 0, 0);
    };

    f32x4 acc[8][4] = {};
    f32x4 av[2][2], bv[4][2];

    // ---- prologue: A0(0), B0(0), B1(1) = 12 loads.
    // vmcnt(4)+barrier => tile-0 landed chip-wide; B1(1) (4 newest) may fly.
    stageA(0, 0, 0); stageA(0, 0, 1);
    stageB(0, 0, 0); stageB(0, 0, 1);
    stageB(1, 1, 0); stageB(1, 1, 1);
    WAITV4;
    BARR;

    for (int i = 0; i < NI; ++i) {
        const int t = 2 * i;
        const bool on = (i + 1 < NI);

        // ======== K-tile t (buffers 0) ========
        READ_BV(0); READ_AV(0, 0);
        stageA(1, t + 1, 0); stageA(1, t + 1, 1);
        BARR; LGKM0; MFMA_Q(0); BARR;
        READ_AV(1, 0);
        if (on) stageB(0, t + 2, 0);
        BARR; LGKM0; MFMA_Q(1); BARR;
        READ_AV(2, 0);
        if (on) stageB(0, t + 2, 1);
        BARR; LGKM0; MFMA_Q(2); BARR;
        // WAIT X before trailing barrier: outstanding = B1(t+1):4 | A1(t+1):4 |
        // B0(t+2):4(newest) -> vmcnt(4) protects phases 4-7. Last iter: vmcnt(0).
        READ_AV(3, 0);
        BARR; LGKM0; MFMA_Q(3);
        if (on) { WAITV4; } else { WAITV0; }
        BARR;

        // ======== K-tile t+1 (buffers 1) ========
        READ_BV(1); READ_AV(0, 1);
        if (on) { stageA(0, t + 2, 0); stageA(0, t + 2, 1); }
        BARR; LGKM0; MFMA_Q(0); BARR;
        READ_AV(1, 1);
        if (on) stageB(1, t + 3, 0);
        BARR; LGKM0; MFMA_Q(1); BARR;
        READ_AV(2, 1);
        if (on) stageB(1, t + 3, 1);
        BARR; LGKM0; MFMA_Q(2); BARR;
        // WAIT Y: outstanding = B0(t+2):4 | A0(t+2):4 | B1(t+3):4(newest) -> vmcnt(4)
        READ_AV(3, 1);
        BARR; LGKM0; MFMA_Q(3);
        if (on) WAITV4;
        BARR;
    }

    // epilogue: plain store (bias added in reduce)
    float* dst = (g == 0) ? out : parts + (size_t)(g - 1) * M_TOK * DDIM;
#pragma unroll
    for (int mf = 0; mf < 8; ++mf)
#pragma unroll
        for (int e = 0; e < 4; ++e) {
            int row = m0 + wm * 128 + mf * 16 + g16 * 4 + e;
#pragma unroll
            for (int j = 0; j < 4; ++j)
                dst[(size_t)row * DDIM + n0 + wn * 64 + j * 16 + ra] = acc[mf][j][e];
        }
}

// ---------------- reduce2: out = out + sum parts + bias(p . bw) ----------------
__global__ __launch_bounds__(256) void reduce2_kernel(
    float* __restrict__ out, const float* __restrict__ parts,
    const float* __restrict__ pmat, const float* __restrict__ bw, int np)
{
    size_t i = (size_t)blockIdx.x * 256 + threadIdx.x;   // float4 idx, 1M total
    int m   = (int)(i >> 8);
    int col = (int)(i & 255) * 4;
    float4 a = ((const float4*)out)[i];
    for (int p = 0; p < np; ++p) {
        float4 b = ((const float4*)(parts + (size_t)p * M_TOK * DDIM))[i];
        a.x += b.x; a.y += b.y; a.z += b.z; a.w += b.w;
    }
    float4 pa = *(const float4*)(pmat + (size_t)m * 8);
    float4 pb = *(const float4*)(pmat + (size_t)m * 8 + 4);
    float4 bias = *(const float4*)(bw + 8 * DDIM + col);
#pragma unroll
    for (int l = 0; l < 8; ++l) {
        float pl = (l < 4) ? ((const float*)&pa)[l] : ((const float*)&pb)[l - 4];
        float4 bl = *(const float4*)(bw + l * DDIM + col);
        bias.x = fmaf(pl, bl.x, bias.x); bias.y = fmaf(pl, bl.y, bias.y);
        bias.z = fmaf(pl, bl.z, bias.z); bias.w = fmaf(pl, bl.w, bias.w);
    }
    a.x += bias.x; a.y += bias.y; a.z += bias.z; a.w += bias.w;
    ((float4*)out)[i] = a;
}

// ================= fallback (round-3 proven): tree_gemm3 + reduce =================
__global__ __launch_bounds__(256, 4) void tree_gemm3(
    const unsigned short* __restrict__ xs, const unsigned short* __restrict__ wp,
    const float* __restrict__ bw, const float* __restrict__ pmat,
    float* __restrict__ out, float* __restrict__ parts, int KG)
{
    __shared__ __align__(16) unsigned short Asm[2][128 * 32];
    __shared__ __align__(16) unsigned short Bsm[2][128 * 32];
    const int tid  = threadIdx.x;
    const int lane = tid & 63;
    const int w    = tid >> 6;
    const int wm   = w >> 1, wn = w & 1;
    const int bx   = blockIdx.x;
    const int xcd  = bx & 7;
    const int ii   = bx >> 3;
    const int mt   = xcd * 4 + (ii >> 3);
    const int nt   = ii & 7;
    const int m0   = mt * 128, n0 = nt * 128;
    const int g    = blockIdx.y;
    const int k0   = g * KG;
    const int ra   = lane & 15;
    const int kb   = (lane >> 4) * 8;
    f32x4 acc[4][4] = {};
    auto stage = [&](int buf, int t) {
#pragma unroll
        for (int c = 0; c < 2; ++c) {
            int row = w * 32 + c * 16 + (lane >> 2);
            int ke  = k0 + t * 32 + (lane & 3) * 8;
            const unsigned short* ga = xs + (size_t)(m0 + row) * KFLAT + ke;
            __builtin_amdgcn_global_load_lds(GLB(ga), LDS(&Asm[buf][w * 1024 + c * 512]), 16, 0, 0);
            const unsigned short* gb = wp + (size_t)(n0 + row) * KFLAT + ke;
            __builtin_amdgcn_global_load_lds(GLB(gb), LDS(&Bsm[buf][w * 1024 + c * 512]), 16, 0, 0);
        }
    };
    const int TOT = KG >> 5;
    stage(0, 0);
    __syncthreads();
    int cur = 0;
    for (int t = 0; t < TOT; ++t) {
        if (t + 1 < TOT) stage(cur ^ 1, t + 1);
        bf16x8 av2[4], bv2[4];
#pragma unroll
        for (int i2 = 0; i2 < 4; ++i2)
            av2[i2] = *(const bf16x8*)&Asm[cur][(wm * 64 + i2 * 16 + ra) * 32 + kb];
#pragma unroll
        for (int j = 0; j < 4; ++j)
            bv2[j] = *(const bf16x8*)&Bsm[cur][(wn * 64 + j * 16 + ra) * 32 + kb];
#pragma unroll
        for (int i2 = 0; i2 < 4; ++i2)
#pragma unroll
            for (int j = 0; j < 4; ++j)
                acc[i2][j] = __builtin_amdgcn_mfma_f32_16x16x32_bf16(av2[i2], bv2[j], acc[i2][j], 0, 0, 0);
        __syncthreads();
        cur ^= 1;
    }
    float* bsm = (float*)&Asm[0][0];
    if (g == 0) {
        for (int idx = tid; idx < 9 * 128; idx += 256)
            bsm[idx] = bw[(idx >> 7) * DDIM + n0 + (idx & 127)];
    }
    __syncthreads();
    float* dst = (g == 0) ? out : parts + (size_t)(g - 1) * M_TOK * DDIM;
#pragma unroll
    for (int i2 = 0; i2 < 4; ++i2)
#pragma unroll
        for (int r = 0; r < 4; ++r) {
            int row = m0 + wm * 64 + i2 * 16 + (lane >> 4) * 4 + r;
            float4 pa, pb;
            if (g == 0) {
                pa = *(const float4*)(pmat + (size_t)row * 8);
                pb = *(const float4*)(pmat + (size_t)row * 8 + 4);
            }
#pragma unroll
            for (int j = 0; j < 4; ++j) {
                int cl = wn * 64 + j * 16 + ra;
                float v = acc[i2][j][r];
                if (g == 0) {
                    v += pa.x * bsm[0 * 128 + cl] + pa.y * bsm[1 * 128 + cl]
                       + pa.z * bsm[2 * 128 + cl] + pa.w * bsm[3 * 128 + cl]
                       + pb.x * bsm[4 * 128 + cl] + pb.y * bsm[5 * 128 + cl]
                       + pb.z * bsm[6 * 128 + cl] + pb.w * bsm[7 * 128 + cl]
                       + bsm[8 * 128 + cl];
                }
                dst[(size_t)row * DDIM + n0 + cl] = v;
            }
        }
}

__global__ __launch_bounds__(256) void reduce_kernel(
    float* __restrict__ out, const float* __restrict__ parts, int np)
{
    size_t i = (size_t)blockIdx.x * 256 + threadIdx.x;
    float4 a = ((const float4*)out)[i];
    for (int p = 0; p < np; ++p) {
        float4 b = ((const float4*)(parts + (size_t)p * M_TOK * DDIM))[i];
        a.x += b.x; a.y += b.y; a.z += b.z; a.w += b.w;
    }
    ((float4*)out)[i] = a;
}

extern "C" void kernel_launch(void* const* d_in, const int* in_sizes, int n_in,
                              void* d_out, int out_size, void* d_ws, size_t ws_size,
                              hipStream_t stream) {
    (void)in_sizes; (void)n_in; (void)out_size;
    const float* x     = (const float*)d_in[0];
    const float* dec_w = (const float*)d_in[1];
    const float* dec_b = (const float*)d_in[2];
    const float* lw    = (const float*)d_in[3];
    const float* lb    = (const float*)d_in[4];
    float* out = (float*)d_out;
    uint8_t* w8 = (uint8_t*)d_ws;

    // layout: xs 72MiB | wp 18MiB | bw 36KiB | pmat 128KiB | parts (ks-1)*16MiB
    unsigned short* xs   = (unsigned short*)(w8);
    unsigned short* wp   = (unsigned short*)(w8 + 75497472);
    float*          bw   = (float*)(w8 + 94371840);
    float*          pmat = (float*)(w8 + 94408704);
    float*          parts= (float*)(w8 + 94539776);
    const size_t NEED3 = 94539776 + 2ull * 16777216;
    const size_t NEED4 = 94539776 + 3ull * 16777216;

    int ks = (ws_size >= NEED4) ? 4 : (ws_size >= NEED3) ? 3 : 0;
    if (!ks) return;

    prep_dec_kernel<<<2048, 256, 0, stream>>>(x, dec_w, dec_b, lw, lb, wp, bw, xs, pmat);

    hipError_t e = hipFuncSetAttribute(
        reinterpret_cast<const void*>(tree_gemm4),
        hipFuncAttributeMaxDynamicSharedMemorySize, 131072);
    if (e == hipSuccess) {
        tree_gemm4<<<dim3(64, ks), 512, 131072, stream>>>(xs, wp, out, parts, KFLAT / ks);
        reduce2_kernel<<<4096, 256, 0, stream>>>(out, parts, pmat, bw, ks - 1);
    } else {
        tree_gemm3<<<dim3(256, ks), 256, 0, stream>>>(xs, wp, bw, pmat, out, parts, KFLAT / ks);
        reduce_kernel<<<4096, 256, 0, stream>>>(out, parts, ks - 1);
    }
}

// Round 7
// 126.206 us; speedup vs baseline: 1.2300x; 1.0091x over previous
//
#include <hip/hip_runtime.h>
#include <stdint.h>

// DecisionTree: out = sum_l p_l * (x @ W_l^T + b_l), p from bottom-layer sigmoids.
// Pair-folded + A-prescaled: ONE flat GEMM A[4096x9216] @ B[1024x9216]^T.
// tree_gemm5: 256x256 tile, BK=64, FLOWING schedule: 1 barrier/K-tile,
// counted vmcnt(4) at boundaries, counted lgkmcnt(4) quadrant pipeline,
// A 2-buf (staged 1 ahead) + B 3-buf (staged 2 ahead) = 160 KB LDS.

#define M_TOK 4096
#define DDIM  1024
#define KFLAT 9216

typedef __bf16 bf16x8 __attribute__((ext_vector_type(8)));
typedef float  f32x4  __attribute__((ext_vector_type(4)));
typedef unsigned short u16x4 __attribute__((ext_vector_type(4)));
typedef unsigned short u16x8 __attribute__((ext_vector_type(8)));

#define GLB(p) ((const __attribute__((address_space(1))) void*)(p))
#define LDS(p) ((__attribute__((address_space(3))) void*)(p))

__device__ __forceinline__ unsigned short f2bf(float f) {
    union { float f; uint32_t u; } v; v.f = f;
    uint32_t u = v.u;
    return (unsigned short)((u + 0x7fffu + ((u >> 16) & 1u)) >> 16);  // RNE
}

__device__ __forceinline__ bf16x8 asbf(f32x4 v) {
    bf16x8 r; __builtin_memcpy(&r, &v, 16); return r;
}

template<int OFF>
__device__ __forceinline__ f32x4 dsr(uint32_t a) {
    f32x4 r;
    asm volatile("ds_read_b128 %0, %1 offset:%c2" : "=v"(r) : "v"(a), "i"(OFF));
    return r;
}

// ---- fused prep: blocks [0,1024) build W'(flat-K) + bias; [1024,2048) build xs + pmat ----
__global__ __launch_bounds__(256) void prep_dec_kernel(
    const float* __restrict__ x, const float* __restrict__ dec_w,
    const float* __restrict__ dec_b, const float* __restrict__ lw,
    const float* __restrict__ lb, unsigned short* __restrict__ wp,
    float* __restrict__ bw, unsigned short* __restrict__ xs,
    float* __restrict__ pmat)
{
    if (blockIdx.x < 1024) {
        int idx = blockIdx.x * 256 + threadIdx.x;     // (o, k/4)
        int o  = idx >> 8;
        int k4 = (idx & 255) << 2;
        size_t src = (size_t)o * DDIM + k4;
        size_t dstb = (size_t)o * KFLAT + k4;
        float4 acc = make_float4(0.f, 0.f, 0.f, 0.f);
#pragma unroll
        for (int j = 0; j < 8; ++j) {
            const float4 a = *(const float4*)(lw + (size_t)(2*j)   * DDIM*DDIM + src);
            const float4 b = *(const float4*)(lw + (size_t)(2*j+1) * DDIM*DDIM + src);
            u16x4 d;
            d[0] = f2bf(a.x - b.x); d[1] = f2bf(a.y - b.y);
            d[2] = f2bf(a.z - b.z); d[3] = f2bf(a.w - b.w);
            *(u16x4*)(wp + dstb + (size_t)j * DDIM) = d;
            acc.x += b.x; acc.y += b.y; acc.z += b.z; acc.w += b.w;
        }
        u16x4 s;
        s[0] = f2bf(acc.x); s[1] = f2bf(acc.y); s[2] = f2bf(acc.z); s[3] = f2bf(acc.w);
        *(u16x4*)(wp + dstb + (size_t)8 * DDIM) = s;
        if ((idx & 255) == 0) {
            float sb = 0.f;
#pragma unroll
            for (int j = 0; j < 8; ++j) {
                float ba = lb[(2*j) * DDIM + o];
                float bb = lb[(2*j+1) * DDIM + o];
                bw[j * DDIM + o] = ba - bb;
                sb += bb;
            }
            bw[8 * DDIM + o] = sb;
        }
    } else {
        int m    = (blockIdx.x - 1024) * 4 + (threadIdx.x >> 6);
        int lane = threadIdx.x & 63;
        const float* xr = x + (size_t)m * DDIM + lane * 16;
        float xv[16];
        *(float4*)&xv[0]  = *(const float4*)(xr + 0);
        *(float4*)&xv[4]  = *(const float4*)(xr + 4);
        *(float4*)&xv[8]  = *(const float4*)(xr + 8);
        *(float4*)&xv[12] = *(const float4*)(xr + 12);
        float s[8];
#pragma unroll
        for (int j = 0; j < 8; ++j) {
            const float* wr = dec_w + (size_t)(7 + j) * DDIM + lane * 16;
            float a = 0.f;
#pragma unroll
            for (int i = 0; i < 16; i += 4) {
                float4 wv = *(const float4*)(wr + i);
                a = fmaf(xv[i], wv.x, fmaf(xv[i+1], wv.y, fmaf(xv[i+2], wv.z, fmaf(xv[i+3], wv.w, a))));
            }
            s[j] = a;
        }
#pragma unroll
        for (int j = 0; j < 8; ++j)
#pragma unroll
            for (int off = 32; off > 0; off >>= 1)
                s[j] += __shfl_xor(s[j], off);
        float p[8];
#pragma unroll
        for (int j = 0; j < 8; ++j)
            p[j] = 1.0f / (1.0f + expf(-(s[j] + dec_b[7 + j])));
        if (lane == 0) {
#pragma unroll
            for (int j = 0; j < 8; ++j)
                pmat[(size_t)m * 8 + j] = p[j];
        }
#pragma unroll
        for (int j = 0; j < 9; ++j) {
            float pj = (j < 8) ? p[j] : 1.0f;
            unsigned short* dst = xs + (size_t)m * KFLAT + j * DDIM + lane * 16;
#pragma unroll
            for (int c = 0; c < 2; ++c) {
                u16x8 o;
#pragma unroll
                for (int e = 0; e < 8; ++e) o[e] = f2bf(pj * xv[c * 8 + e]);
                *(u16x8*)(dst + c * 8) = o;
            }
        }
    }
}

// ---- shared wait/MFMA macros ----
#define WAITV8 asm volatile("s_waitcnt vmcnt(8)" ::: "memory")
#define WAITV4 asm volatile("s_waitcnt vmcnt(4)" ::: "memory")
#define WAITV0 asm volatile("s_waitcnt vmcnt(0)" ::: "memory")
#define BARR   __builtin_amdgcn_s_barrier()
#define LGKM0  do { asm volatile("s_waitcnt lgkmcnt(0)" ::: "memory"); \
                    __builtin_amdgcn_sched_barrier(0); } while(0)
#define LGKM4  do { asm volatile("s_waitcnt lgkmcnt(4)" ::: "memory"); \
                    __builtin_amdgcn_sched_barrier(0); } while(0)

#define MFMA_Q(q, SET) do { \
    __builtin_amdgcn_s_setprio(1); \
    _Pragma("unroll") \
    for (int mfl = 0; mfl < 2; ++mfl) { \
        _Pragma("unroll") \
        for (int j = 0; j < 4; ++j) { \
            acc[2*(q)+mfl][j] = __builtin_amdgcn_mfma_f32_16x16x32_bf16(asbf(SET[mfl][0]), asbf(bv[j][0]), acc[2*(q)+mfl][j], 0, 0, 0); \
            acc[2*(q)+mfl][j] = __builtin_amdgcn_mfma_f32_16x16x32_bf16(asbf(SET[mfl][1]), asbf(bv[j][1]), acc[2*(q)+mfl][j], 0, 0, 0); \
        } \
    } \
    __builtin_amdgcn_s_setprio(0); \
} while(0)

#define READ_A(SET, q) do { \
    SET[0][0] = dsr<(2*(q)+0)*2048>(bA0); \
    SET[0][1] = dsr<(2*(q)+0)*2048>(bA1); \
    SET[1][0] = dsr<(2*(q)+1)*2048>(bA0); \
    SET[1][1] = dsr<(2*(q)+1)*2048>(bA1); \
} while(0)

#define READ_B() do { \
    bv[0][0] = dsr<0*2048>(bB0); bv[0][1] = dsr<0*2048>(bB1); \
    bv[1][0] = dsr<1*2048>(bB0); bv[1][1] = dsr<1*2048>(bB1); \
    bv[2][0] = dsr<2*2048>(bB0); bv[2][1] = dsr<2*2048>(bB1); \
    bv[3][0] = dsr<3*2048>(bB0); bv[3][1] = dsr<3*2048>(bB1); \
} while(0)

// ================= tree_gemm5: flowing schedule, 160 KB LDS =================
// LDS: A0@0 A1@32K | B0@64K B1@96K B2@128K. Row = 128 B; G4 swizzle
// (byte ^= (row&7)<<4) via linear gload_lds dest + inverse-XORed global src.
__global__ __launch_bounds__(512, 2) void tree_gemm5(
    const unsigned short* __restrict__ xs,   // [4096][9216] bf16
    const unsigned short* __restrict__ wp,   // [1024][9216] bf16
    float* __restrict__ out, float* __restrict__ parts,
    int KG)
{
    extern __shared__ char smem[];
    const int tid  = threadIdx.x;
    const int lane = tid & 63;
    const int w    = tid >> 6;
    const int wm   = w >> 2, wn = w & 3;     // 2M x 4N waves
    const int ra   = lane & 15;
    const int g16  = lane >> 4;

    const int bx  = blockIdx.x;
    const int xcd = bx & 7, ii = bx >> 3;
    const int nt  = xcd >> 1;
    const int mt  = (xcd & 1) * 8 + ii;
    const int m0  = mt * 256, n0 = nt * 256;
    const int g   = blockIdx.y;
    const int k0  = g * KG;
    const int NT  = KG >> 6;                 // K-tiles (1 per loop iter)

    uint32_t sbase = (uint32_t)(uintptr_t)(__attribute__((address_space(3))) char*)smem;
    const uint32_t colb0 = (uint32_t)((g16 ^ (ra & 7)) << 4);
    const uint32_t colb1 = colb0 ^ 64;
    const uint32_t baseA0s = sbase + wm * 16384 + ra * 128 + colb0;
    const uint32_t baseA1s = sbase + wm * 16384 + ra * 128 + colb1;
    const uint32_t baseB0s = sbase + 65536 + wn * 8192 + ra * 128 + colb0;
    const uint32_t baseB1s = sbase + 65536 + wn * 8192 + ra * 128 + colb1;

    const int kel = (((lane & 7) ^ (lane >> 3)) & 7) * 8;
    const int rA  = w * 8 + (lane >> 3);

    auto stageA = [&](int buf, int tt, int hh) {
        const unsigned short* s0 = xs + (size_t)(m0 + hh * 128 + rA) * KFLAT + (k0 + tt * 64 + kel);
        char* d0 = smem + buf * 32768 + hh * 16384 + w * 1024;
        __builtin_amdgcn_global_load_lds(GLB(s0), LDS(d0), 16, 0, 0);
        __builtin_amdgcn_global_load_lds(GLB(s0 + (size_t)64 * KFLAT), LDS(d0 + 8192), 16, 0, 0);
    };
    auto stageB = [&](int buf, int tt, int hh) {
        const unsigned short* s0 = wp + (size_t)(n0 + hh * 128 + rA) * KFLAT + (k0 + tt * 64 + kel);
        char* d0 = smem + 65536 + buf * 32768 + hh * 16384 + w * 1024;
        __builtin_amdgcn_global_load_lds(GLB(s0), LDS(d0), 16, 0, 0);
        __builtin_amdgcn_global_load_lds(GLB(s0 + (size_t)64 * KFLAT), LDS(d0 + 8192), 16, 0, 0);
    };

    f32x4 acc[8][4] = {};
    f32x4 avA[2][2], avB[2][2], bv[4][2];

    // prologue: A(0)->A0, B(0)->B0, A(1)->A1, B(1)->B1 (16 loads).
    // vmcnt(8)+barrier: tile-0 buffers landed; A1,B1 (8 newest) may fly.
    stageA(0, 0, 0); stageA(0, 0, 1);
    stageB(0, 0, 0); stageB(0, 0, 1);
    stageA(1, 1, 0); stageA(1, 1, 1);
    stageB(1, 1, 0); stageB(1, 1, 1);
    WAITV8;
    BARR;

    int bt = 0, bt2 = 2;                     // t%3, (t+2)%3
    for (int t = 0; t < NT; ++t) {
        // ---- boundary (t>0): vmcnt(4) leaves only B(t+1)'s 4 loads in flight;
        // A(t) + B(t) + everything older has landed. Last boundary: vmcnt(0).
        if (t) {
            if (t == NT - 1) { WAITV0; } else { WAITV4; }
            BARR;
        }
        // ---- stage tile t+1's A (1 ahead) and tile t+2's B (2 ahead).
        // Targets were last read in tile t-1 => boundary barrier covers WAR.
        if (t + 1 < NT) { stageA((t + 1) & 1, t + 1, 0); stageA((t + 1) & 1, t + 1, 1); }
        if (t + 2 < NT) { stageB(bt2, t + 2, 0); stageB(bt2, t + 2, 1); }

        // ---- per-tile read bases
        const uint32_t aoff = (uint32_t)(t & 1) << 15;
        const uint32_t boff = (uint32_t)bt << 15;
        const uint32_t bA0 = baseA0s + aoff, bA1 = baseA1s + aoff;
        const uint32_t bB0 = baseB0s + boff, bB1 = baseB1s + boff;

        // ---- quadrant-pipelined compute: reads one quadrant ahead, counted lgkm.
        READ_B();                 // 8 reads
        READ_A(avA, 0);           // 12
        READ_A(avB, 1);           // 16
        LGKM4;  MFMA_Q(0, avA);   // B + q0 done; q1 in flight
        READ_A(avA, 2);           // q1(4) + q2(4)
        LGKM4;  MFMA_Q(1, avB);   // q1 done; q2 in flight
        READ_A(avB, 3);           // q2(4) + q3(4)
        LGKM4;  MFMA_Q(2, avA);   // q2 done; q3 in flight
        LGKM0;  MFMA_Q(3, avB);   // q3 done

        bt  = (bt  == 2) ? 0 : bt  + 1;
        bt2 = (bt2 == 2) ? 0 : bt2 + 1;
    }

    // epilogue: plain store (bias added in reduce)
    float* dst = (g == 0) ? out : parts + (size_t)(g - 1) * M_TOK * DDIM;
#pragma unroll
    for (int mf = 0; mf < 8; ++mf)
#pragma unroll
        for (int e = 0; e < 4; ++e) {
            int row = m0 + wm * 128 + mf * 16 + g16 * 4 + e;
#pragma unroll
            for (int j = 0; j < 4; ++j)
                dst[(size_t)row * DDIM + n0 + wn * 64 + j * 16 + ra] = acc[mf][j][e];
        }
}

// ================= tree_gemm4 (round-6 proven, 128 KB): fallback #1 =================
#define READ_AV4(q, b) do { \
    avA[0][0] = dsr<(b)*32768 + (2*(q)+0)*2048>(baseA0); \
    avA[0][1] = dsr<(b)*32768 + (2*(q)+0)*2048>(baseA1); \
    avA[1][0] = dsr<(b)*32768 + (2*(q)+1)*2048>(baseA0); \
    avA[1][1] = dsr<(b)*32768 + (2*(q)+1)*2048>(baseA1); \
} while(0)

#define READ_BV4(b) do { \
    bv[0][0] = dsr<(b)*32768 + 0*2048>(baseB0); bv[0][1] = dsr<(b)*32768 + 0*2048>(baseB1); \
    bv[1][0] = dsr<(b)*32768 + 1*2048>(baseB0); bv[1][1] = dsr<(b)*32768 + 1*2048>(baseB1); \
    bv[2][0] = dsr<(b)*32768 + 2*2048>(baseB0); bv[2][1] = dsr<(b)*32768 + 2*2048>(baseB1); \
    bv[3][0] = dsr<(b)*32768 + 3*2048>(baseB0); bv[3][1] = dsr<(b)*32768 + 3*2048>(baseB1); \
} while(0)

__global__ __launch_bounds__(512, 2) void tree_gemm4(
    const unsigned short* __restrict__ xs, const unsigned short* __restrict__ wp,
    float* __restrict__ out, float* __restrict__ parts, int KG)
{
    extern __shared__ char smem[];
    const int tid  = threadIdx.x;
    const int lane = tid & 63;
    const int w    = tid >> 6;
    const int wm   = w >> 2, wn = w & 3;
    const int ra   = lane & 15;
    const int g16  = lane >> 4;
    const int bx  = blockIdx.x;
    const int xcd = bx & 7, ii = bx >> 3;
    const int nt  = xcd >> 1;
    const int mt  = (xcd & 1) * 8 + ii;
    const int m0  = mt * 256, n0 = nt * 256;
    const int g   = blockIdx.y;
    const int k0  = g * KG;
    const int NI  = KG >> 7;
    uint32_t sbase = (uint32_t)(uintptr_t)(__attribute__((address_space(3))) char*)smem;
    const uint32_t colb0 = (uint32_t)((g16 ^ (ra & 7)) << 4);
    const uint32_t colb1 = colb0 ^ 64;
    const uint32_t baseA0 = sbase + wm * 16384 + ra * 128 + colb0;
    const uint32_t baseA1 = sbase + wm * 16384 + ra * 128 + colb1;
    const uint32_t baseB0 = sbase + 65536 + wn * 8192 + ra * 128 + colb0;
    const uint32_t baseB1 = sbase + 65536 + wn * 8192 + ra * 128 + colb1;
    const int kel = (((lane & 7) ^ (lane >> 3)) & 7) * 8;
    const int rA  = w * 8 + (lane >> 3);
    auto stageA = [&](int buf, int tt, int hh) {
        const unsigned short* s0 = xs + (size_t)(m0 + hh * 128 + rA) * KFLAT + (k0 + tt * 64 + kel);
        char* d0 = smem + buf * 32768 + hh * 16384 + w * 1024;
        __builtin_amdgcn_global_load_lds(GLB(s0), LDS(d0), 16, 0, 0);
        __builtin_amdgcn_global_load_lds(GLB(s0 + (size_t)64 * KFLAT), LDS(d0 + 8192), 16, 0, 0);
    };
    auto stageB = [&](int buf, int tt, int hh) {
        const unsigned short* s0 = wp + (size_t)(n0 + hh * 128 + rA) * KFLAT + (k0 + tt * 64 + kel);
        char* d0 = smem + 65536 + buf * 32768 + hh * 16384 + w * 1024;
        __builtin_amdgcn_global_load_lds(GLB(s0), LDS(d0), 16, 0, 0);
        __builtin_amdgcn_global_load_lds(GLB(s0 + (size_t)64 * KFLAT), LDS(d0 + 8192), 16, 0, 0);
    };
    f32x4 acc[8][4] = {};
    f32x4 avA[2][2], bv[4][2];
    stageA(0, 0, 0); stageA(0, 0, 1);
    stageB(0, 0, 0); stageB(0, 0, 1);
    stageB(1, 1, 0); stageB(1, 1, 1);
    WAITV4; BARR;
    for (int i = 0; i < NI; ++i) {
        const int t = 2 * i;
        const bool on = (i + 1 < NI);
        READ_BV4(0); READ_AV4(0, 0);
        stageA(1, t + 1, 0); stageA(1, t + 1, 1);
        BARR; LGKM0; MFMA_Q(0, avA); BARR;
        READ_AV4(1, 0); if (on) stageB(0, t + 2, 0);
        BARR; LGKM0; MFMA_Q(1, avA); BARR;
        READ_AV4(2, 0); if (on) stageB(0, t + 2, 1);
        BARR; LGKM0; MFMA_Q(2, avA); BARR;
        READ_AV4(3, 0);
        BARR; LGKM0; MFMA_Q(3, avA);
        if (on) { WAITV4; } else { WAITV0; }
        BARR;
        READ_BV4(1); READ_AV4(0, 1);
        if (on) { stageA(0, t + 2, 0); stageA(0, t + 2, 1); }
        BARR; LGKM0; MFMA_Q(0, avA); BARR;
        READ_AV4(1, 1); if (on) stageB(1, t + 3, 0);
        BARR; LGKM0; MFMA_Q(1, avA); BARR;
        READ_AV4(2, 1); if (on) stageB(1, t + 3, 1);
        BARR; LGKM0; MFMA_Q(2, avA); BARR;
        READ_AV4(3, 1);
        BARR; LGKM0; MFMA_Q(3, avA);
        if (on) WAITV4;
        BARR;
    }
    float* dst = (g == 0) ? out : parts + (size_t)(g - 1) * M_TOK * DDIM;
#pragma unroll
    for (int mf = 0; mf < 8; ++mf)
#pragma unroll
        for (int e = 0; e < 4; ++e) {
            int row = m0 + wm * 128 + mf * 16 + g16 * 4 + e;
#pragma unroll
            for (int j = 0; j < 4; ++j)
                dst[(size_t)row * DDIM + n0 + wn * 64 + j * 16 + ra] = acc[mf][j][e];
        }
}

// ---------------- reduce2: out = out + sum parts + bias(p . bw) ----------------
__global__ __launch_bounds__(256) void reduce2_kernel(
    float* __restrict__ out, const float* __restrict__ parts,
    const float* __restrict__ pmat, const float* __restrict__ bw, int np)
{
    size_t i = (size_t)blockIdx.x * 256 + threadIdx.x;
    int m   = (int)(i >> 8);
    int col = (int)(i & 255) * 4;
    float4 a = ((const float4*)out)[i];
    for (int p = 0; p < np; ++p) {
        float4 b = ((const float4*)(parts + (size_t)p * M_TOK * DDIM))[i];
        a.x += b.x; a.y += b.y; a.z += b.z; a.w += b.w;
    }
    float4 pa = *(const float4*)(pmat + (size_t)m * 8);
    float4 pb = *(const float4*)(pmat + (size_t)m * 8 + 4);
    float4 bias = *(const float4*)(bw + 8 * DDIM + col);
#pragma unroll
    for (int l = 0; l < 8; ++l) {
        float pl = (l < 4) ? ((const float*)&pa)[l] : ((const float*)&pb)[l - 4];
        float4 bl = *(const float4*)(bw + l * DDIM + col);
        bias.x = fmaf(pl, bl.x, bias.x); bias.y = fmaf(pl, bl.y, bias.y);
        bias.z = fmaf(pl, bl.z, bias.z); bias.w = fmaf(pl, bl.w, bias.w);
    }
    a.x += bias.x; a.y += bias.y; a.z += bias.z; a.w += bias.w;
    ((float4*)out)[i] = a;
}

// ================= fallback #2 (round-3 proven): tree_gemm3 + reduce =================
__global__ __launch_bounds__(256, 4) void tree_gemm3(
    const unsigned short* __restrict__ xs, const unsigned short* __restrict__ wp,
    const float* __restrict__ bw, const float* __restrict__ pmat,
    float* __restrict__ out, float* __restrict__ parts, int KG)
{
    __shared__ __align__(16) unsigned short Asm[2][128 * 32];
    __shared__ __align__(16) unsigned short Bsm[2][128 * 32];
    const int tid  = threadIdx.x;
    const int lane = tid & 63;
    const int w    = tid >> 6;
    const int wm   = w >> 1, wn = w & 1;
    const int bx   = blockIdx.x;
    const int xcd  = bx & 7;
    const int ii   = bx >> 3;
    const int mt   = xcd * 4 + (ii >> 3);
    const int nt   = ii & 7;
    const int m0   = mt * 128, n0 = nt * 128;
    const int g    = blockIdx.y;
    const int k0   = g * KG;
    const int ra   = lane & 15;
    const int kb   = (lane >> 4) * 8;
    f32x4 acc[4][4] = {};
    auto stage = [&](int buf, int t) {
#pragma unroll
        for (int c = 0; c < 2; ++c) {
            int row = w * 32 + c * 16 + (lane >> 2);
            int ke  = k0 + t * 32 + (lane & 3) * 8;
            const unsigned short* ga = xs + (size_t)(m0 + row) * KFLAT + ke;
            __builtin_amdgcn_global_load_lds(GLB(ga), LDS(&Asm[buf][w * 1024 + c * 512]), 16, 0, 0);
            const unsigned short* gb = wp + (size_t)(n0 + row) * KFLAT + ke;
            __builtin_amdgcn_global_load_lds(GLB(gb), LDS(&Bsm[buf][w * 1024 + c * 512]), 16, 0, 0);
        }
    };
    const int TOT = KG >> 5;
    stage(0, 0);
    __syncthreads();
    int cur = 0;
    for (int t = 0; t < TOT; ++t) {
        if (t + 1 < TOT) stage(cur ^ 1, t + 1);
        bf16x8 av2[4], bv2[4];
#pragma unroll
        for (int i2 = 0; i2 < 4; ++i2)
            av2[i2] = *(const bf16x8*)&Asm[cur][(wm * 64 + i2 * 16 + ra) * 32 + kb];
#pragma unroll
        for (int j = 0; j < 4; ++j)
            bv2[j] = *(const bf16x8*)&Bsm[cur][(wn * 64 + j * 16 + ra) * 32 + kb];
#pragma unroll
        for (int i2 = 0; i2 < 4; ++i2)
#pragma unroll
            for (int j = 0; j < 4; ++j)
                acc[i2][j] = __builtin_amdgcn_mfma_f32_16x16x32_bf16(av2[i2], bv2[j], acc[i2][j], 0, 0, 0);
        __syncthreads();
        cur ^= 1;
    }
    float* bsm = (float*)&Asm[0][0];
    if (g == 0) {
        for (int idx = tid; idx < 9 * 128; idx += 256)
            bsm[idx] = bw[(idx >> 7) * DDIM + n0 + (idx & 127)];
    }
    __syncthreads();
    float* dst = (g == 0) ? out : parts + (size_t)(g - 1) * M_TOK * DDIM;
#pragma unroll
    for (int i2 = 0; i2 < 4; ++i2)
#pragma unroll
        for (int r = 0; r < 4; ++r) {
            int row = m0 + wm * 64 + i2 * 16 + (lane >> 4) * 4 + r;
            float4 pa, pb;
            if (g == 0) {
                pa = *(const float4*)(pmat + (size_t)row * 8);
                pb = *(const float4*)(pmat + (size_t)row * 8 + 4);
            }
#pragma unroll
            for (int j = 0; j < 4; ++j) {
                int cl = wn * 64 + j * 16 + ra;
                float v = acc[i2][j][r];
                if (g == 0) {
                    v += pa.x * bsm[0 * 128 + cl] + pa.y * bsm[1 * 128 + cl]
                       + pa.z * bsm[2 * 128 + cl] + pa.w * bsm[3 * 128 + cl]
                       + pb.x * bsm[4 * 128 + cl] + pb.y * bsm[5 * 128 + cl]
                       + pb.z * bsm[6 * 128 + cl] + pb.w * bsm[7 * 128 + cl]
                       + bsm[8 * 128 + cl];
                }
                dst[(size_t)row * DDIM + n0 + cl] = v;
            }
        }
}

__global__ __launch_bounds__(256) void reduce_kernel(
    float* __restrict__ out, const float* __restrict__ parts, int np)
{
    size_t i = (size_t)blockIdx.x * 256 + threadIdx.x;
    float4 a = ((const float4*)out)[i];
    for (int p = 0; p < np; ++p) {
        float4 b = ((const float4*)(parts + (size_t)p * M_TOK * DDIM))[i];
        a.x += b.x; a.y += b.y; a.z += b.z; a.w += b.w;
    }
    ((float4*)out)[i] = a;
}

extern "C" void kernel_launch(void* const* d_in, const int* in_sizes, int n_in,
                              void* d_out, int out_size, void* d_ws, size_t ws_size,
                              hipStream_t stream) {
    (void)in_sizes; (void)n_in; (void)out_size;
    const float* x     = (const float*)d_in[0];
    const float* dec_w = (const float*)d_in[1];
    const float* dec_b = (const float*)d_in[2];
    const float* lw    = (const float*)d_in[3];
    const float* lb    = (const float*)d_in[4];
    float* out = (float*)d_out;
    uint8_t* w8 = (uint8_t*)d_ws;

    unsigned short* xs   = (unsigned short*)(w8);
    unsigned short* wp   = (unsigned short*)(w8 + 75497472);
    float*          bw   = (float*)(w8 + 94371840);
    float*          pmat = (float*)(w8 + 94408704);
    float*          parts= (float*)(w8 + 94539776);
    const size_t NEED3 = 94539776 + 2ull * 16777216;
    const size_t NEED4 = 94539776 + 3ull * 16777216;

    int ks = (ws_size >= NEED4) ? 4 : (ws_size >= NEED3) ? 3 : 0;
    if (!ks) return;

    prep_dec_kernel<<<2048, 256, 0, stream>>>(x, dec_w, dec_b, lw, lb, wp, bw, xs, pmat);

    hipError_t e5 = hipFuncSetAttribute(
        reinterpret_cast<const void*>(tree_gemm5),
        hipFuncAttributeMaxDynamicSharedMemorySize, 163840);
    if (e5 == hipSuccess) {
        tree_gemm5<<<dim3(64, ks), 512, 163840, stream>>>(xs, wp, out, parts, KFLAT / ks);
        reduce2_kernel<<<4096, 256, 0, stream>>>(out, parts, pmat, bw, ks - 1);
        return;
    }
    hipError_t e4 = hipFuncSetAttribute(
        reinterpret_cast<const void*>(tree_gemm4),
        hipFuncAttributeMaxDynamicSharedMemorySize, 131072);
    if (e4 == hipSuccess) {
        tree_gemm4<<<dim3(64, ks), 512, 131072, stream>>>(xs, wp, out, parts, KFLAT / ks);
        reduce2_kernel<<<4096, 256, 0, stream>>>(out, parts, pmat, bw, ks - 1);
    } else {
        tree_gemm3<<<dim3(256, ks), 256, 0, stream>>>(xs, wp, bw, pmat, out, parts, KFLAT / ks);
        reduce_kernel<<<4096, 256, 0, stream>>>(out, parts, ks - 1);
    }
}